// Round 1
// baseline (7071.938 us; speedup 1.0000x reference)
//
#include <hip/hip_runtime.h>

// ---------------------------------------------------------------------------
// TransformerDecoder forward on MI355X (gfx950).
// B=4, S=SR=512, H=1024, NH=16, HD=64, L=6, V=32000, FF=4096, PAD=2
// Strategy: everything matmul-shaped goes through one generic batched
// bf16-MFMA GEMM (f32 in / f32 out, bf16 convert at LDS staging).
// ---------------------------------------------------------------------------

typedef short s16x8 __attribute__((ext_vector_type(8)));
typedef float f32x4 __attribute__((ext_vector_type(4)));

#define PADTOK 2
#define NEG_INF (-__builtin_inff())

// round-to-nearest-even f32 -> bf16 (bit trick; inputs are finite)
static __device__ __forceinline__ unsigned short f2bf(float f) {
  unsigned u = __float_as_uint(f);
  u += 0x7fffu + ((u >> 16) & 1u);
  return (unsigned short)(u >> 16);
}

static __device__ __forceinline__ f32x4 mfma16(s16x8 a, s16x8 b, f32x4 c) {
  asm("v_mfma_f32_16x16x32_bf16 %0, %1, %2, %0" : "+v"(c) : "v"(a), "v"(b));
  return c;
}

// ---------------------------------------------------------------------------
// Generic batched GEMM: C = epilogue(A[M,K] @ B[K,N]) per batch g (grid.z).
// A,B,C are f32 in global; bf16 MFMA internally. BM=BN=128, BK=32, 256 thr.
// EPI: 0 plain (C + g*sCg + m*ldc + n)
//      1 head-split  [b,h,s,d]   (m=(b,s) over S=512, n=(h,d) over HD=64)
//      2 head-split-T [b,h,d,s]
//      3 head-merge  from batched g=(b,h): out[b, m, h*64+n] (H=1024)
// Requirements honored by all call sites: M%128==0, K%32==0. N is guarded.
// ---------------------------------------------------------------------------
template<int EPI, bool RELU, bool RESID>
__global__ __launch_bounds__(256)
void gemm_kernel(const float* __restrict__ A, int lda, long long sAg,
                 const float* __restrict__ B, int ldb, long long sBg,
                 const float* __restrict__ bias,
                 const float* __restrict__ Res,
                 float* __restrict__ C, int ldc, long long sCg,
                 int M, int N, int K, float scale)
{
  __shared__ unsigned short As[128][40];  // [m][k], +8 pad
  __shared__ unsigned short Bs[128][40];  // [n][k] (transposed), +8 pad
  const int g = blockIdx.z;
  const float* Ag = A + (size_t)g * (size_t)sAg;
  const float* Bg = B + (size_t)g * (size_t)sBg;
  const int bm0 = blockIdx.y * 128, bn0 = blockIdx.x * 128;
  const int tid = threadIdx.x, lane = tid & 63;
  const int wm = (tid >> 6) >> 1, wn = (tid >> 6) & 1;

  f32x4 acc[4][4];
#pragma unroll
  for (int i = 0; i < 4; ++i)
#pragma unroll
    for (int j = 0; j < 4; ++j) acc[i][j] = (f32x4){0.f, 0.f, 0.f, 0.f};

  const int ar = tid >> 1, akh = tid & 1;      // A staging: row, k-half
  const int bn = tid & 127, bkh = tid >> 7;    // B staging: col, k-half
  const int bng = bn0 + bn;
  const float* Aprow = Ag + (size_t)(bm0 + ar) * (size_t)lda + akh * 16;
  const int rsel = lane & 15, kg = lane >> 4;

  for (int k0 = 0; k0 < K; k0 += 32) {
    __syncthreads();
    {  // stage A: 16 contiguous k per thread (4x float4), convert, 2x b128 write
      const float4* ap = (const float4*)(Aprow + k0);
      unsigned short ab[16];
#pragma unroll
      for (int q = 0; q < 4; ++q) {
        float4 t = ap[q];
        ab[4*q+0] = f2bf(t.x); ab[4*q+1] = f2bf(t.y);
        ab[4*q+2] = f2bf(t.z); ab[4*q+3] = f2bf(t.w);
      }
      *(s16x8*)&As[ar][akh*16]     = *(s16x8*)&ab[0];
      *(s16x8*)&As[ar][akh*16 + 8] = *(s16x8*)&ab[8];
    }
    {  // stage B transposed: 16 k-strided loads at column bng (coalesced per k)
      unsigned short bb[16];
#pragma unroll
      for (int q = 0; q < 16; ++q) {
        int kk = k0 + bkh*16 + q;
        float v = (bng < N) ? Bg[(size_t)kk * (size_t)ldb + bng] : 0.f;
        bb[q] = f2bf(v);
      }
      *(s16x8*)&Bs[bn][bkh*16]     = *(s16x8*)&bb[0];
      *(s16x8*)&Bs[bn][bkh*16 + 8] = *(s16x8*)&bb[8];
    }
    __syncthreads();

    s16x8 af[4], bf[4];
#pragma unroll
    for (int mf = 0; mf < 4; ++mf) af[mf] = *(s16x8*)&As[wm*64 + mf*16 + rsel][kg*8];
#pragma unroll
    for (int nf = 0; nf < 4; ++nf) bf[nf] = *(s16x8*)&Bs[wn*64 + nf*16 + rsel][kg*8];
#pragma unroll
    for (int mf = 0; mf < 4; ++mf)
#pragma unroll
      for (int nf = 0; nf < 4; ++nf)
        acc[mf][nf] = mfma16(af[mf], bf[nf], acc[mf][nf]);
  }

  // epilogue: C/D layout col=lane&15, row=(lane>>4)*4+e
#pragma unroll
  for (int mf = 0; mf < 4; ++mf) {
#pragma unroll
    for (int nf = 0; nf < 4; ++nf) {
      int n = bn0 + wn*64 + nf*16 + rsel;
      if (n >= N) continue;
#pragma unroll
      for (int e = 0; e < 4; ++e) {
        int m = bm0 + wm*64 + mf*16 + kg*4 + e;
        float v = acc[mf][nf][e];
        if (bias) v += bias[n];
        v *= scale;
        if constexpr (RELU) v = fmaxf(v, 0.f);
        if constexpr (RESID) v += Res[(size_t)m * (size_t)ldc + n];
        size_t idx;
        if constexpr (EPI == 0)
          idx = (size_t)g * (size_t)sCg + (size_t)m * (size_t)ldc + (size_t)n;
        else if constexpr (EPI == 1)
          idx = ((size_t)(m >> 9)) * 524288u + ((size_t)(n >> 6)) * 32768u
              + (size_t)(m & 511) * 64u + (size_t)(n & 63);
        else if constexpr (EPI == 2)
          idx = ((size_t)(m >> 9)) * 524288u + ((size_t)(n >> 6)) * 32768u
              + (size_t)(n & 63) * 512u + (size_t)(m & 511);
        else
          idx = ((size_t)(g >> 4)) * 524288u + (size_t)m * 1024u
              + (size_t)(g & 15) * 64u + (size_t)n;
        C[idx] = v;
      }
    }
  }
}

// ---------------------------------------------------------------------------
// reductions (blocks are always 256 threads = 4 waves)
// ---------------------------------------------------------------------------
static __device__ __forceinline__ float wred_sum(float v) {
#pragma unroll
  for (int o = 32; o > 0; o >>= 1) v += __shfl_down(v, o, 64);
  return v;
}
static __device__ __forceinline__ float wred_max(float v) {
#pragma unroll
  for (int o = 32; o > 0; o >>= 1) v = fmaxf(v, __shfl_down(v, o, 64));
  return v;
}
static __device__ __forceinline__ float bred_sum(float v, float* sm) {
  int lane = threadIdx.x & 63, wid = threadIdx.x >> 6;
  v = wred_sum(v);
  if (lane == 0) sm[wid] = v;
  __syncthreads();
  if (threadIdx.x == 0) sm[0] = sm[0] + sm[1] + sm[2] + sm[3];
  __syncthreads();
  float r = sm[0];
  __syncthreads();
  return r;
}
static __device__ __forceinline__ float bred_max(float v, float* sm) {
  int lane = threadIdx.x & 63, wid = threadIdx.x >> 6;
  v = wred_max(v);
  if (lane == 0) sm[wid] = v;
  __syncthreads();
  if (threadIdx.x == 0) sm[0] = fmaxf(fmaxf(sm[0], sm[1]), fmaxf(sm[2], sm[3]));
  __syncthreads();
  float r = sm[0];
  __syncthreads();
  return r;
}

// ---------------------------------------------------------------------------
// small kernels
// ---------------------------------------------------------------------------
__global__ void embed_kernel(const int* __restrict__ dec,
                             const float* __restrict__ emb,
                             float* __restrict__ X) {
  int m = blockIdx.x;
  int tok = dec[m];
  const float4* s = (const float4*)(emb + (size_t)tok * 1024u);
  float4* d = (float4*)(X + (size_t)m * 1024u);
  d[threadIdx.x] = s[threadIdx.x];
}

// pos: [1023][64] layer slice -> PT[64][512] (only rel rows 0..511 are used)
__global__ void transpose_pos(const float* __restrict__ pos, float* __restrict__ PT) {
  int idx = blockIdx.x * 256 + threadIdx.x;  // 64*512 total
  int d = idx >> 9, r = idx & 511;
  PT[idx] = pos[(size_t)r * 64u + (size_t)d];
}

__global__ void layernorm_kernel(const float* __restrict__ R,
                                 const float* __restrict__ gw,
                                 const float* __restrict__ bw,
                                 float* __restrict__ Y) {
  __shared__ float sm[4];
  int m = blockIdx.x, t = threadIdx.x;
  float4 v = ((const float4*)(R + (size_t)m * 1024u))[t];
  float s = v.x + v.y + v.z + v.w;
  s = bred_sum(s, sm);
  float mean = s * (1.f / 1024.f);
  float d0 = v.x - mean, d1 = v.y - mean, d2 = v.z - mean, d3 = v.w - mean;
  float q = d0*d0 + d1*d1 + d2*d2 + d3*d3;
  q = bred_sum(q, sm);
  float rstd = rsqrtf(q * (1.f / 1024.f) + 1e-5f);
  int c = t * 4;
  float4 o;
  o.x = d0 * rstd * gw[c+0] + bw[c+0];
  o.y = d1 * rstd * gw[c+1] + bw[c+1];
  o.z = d2 * rstd * gw[c+2] + bw[c+2];
  o.w = d3 * rstd * gw[c+3] + bw[c+3];
  ((float4*)(Y + (size_t)m * 1024u))[t] = o;
}

// self-attn softmax: scores += skew (PE lookup) + causal + pad mask, softmax row
// grid = (512 rows i, 64 batch-heads g), 256 threads (2 cols each)
__global__ void softmax_self(float* __restrict__ SC, const float* __restrict__ PE,
                             const int* __restrict__ dec) {
  __shared__ float sm[4];
  int i = blockIdx.x, g = blockIdx.y, b = g >> 4;
  int t = threadIdx.x;
  float* row = SC + ((size_t)(g * 512 + i)) * 512u;
  const float* pe = PE + ((size_t)(g * 512 + i)) * 512u;
  float v0, v1;
  {
    int j = t;
    bool ok = (j <= i) && (dec[b * 512 + j] != PADTOK);
    int r = (j <= i) ? (511 + j - i) : 0;       // clamped: no OOB even if speculated
    v0 = ok ? (row[j] + pe[r]) : NEG_INF;
    j = t + 256;
    ok = (j <= i) && (dec[b * 512 + j] != PADTOK);
    r = (j <= i) ? (511 + j - i) : 0;
    v1 = ok ? (row[j] + pe[r]) : NEG_INF;
  }
  float mx = bred_max(fmaxf(v0, v1), sm);
  float e0 = expf(v0 - mx), e1 = expf(v1 - mx);
  float s = bred_sum(e0 + e1, sm);
  float inv = 1.f / s;
  row[t] = e0 * inv;
  row[t + 256] = e1 * inv;
}

__global__ void softmax_cross(float* __restrict__ SC, const int* __restrict__ enc) {
  __shared__ float sm[4];
  int i = blockIdx.x, g = blockIdx.y, b = g >> 4;
  int t = threadIdx.x;
  float* row = SC + ((size_t)(g * 512 + i)) * 512u;
  float v0 = (enc[b * 512 + t]       == PADTOK) ? NEG_INF : row[t];
  float v1 = (enc[b * 512 + t + 256] == PADTOK) ? NEG_INF : row[t + 256];
  float mx = bred_max(fmaxf(v0, v1), sm);
  float e0 = expf(v0 - mx), e1 = expf(v1 - mx);
  float s = bred_sum(e0 + e1, sm);
  float inv = 1.f / s;
  row[t] = e0 * inv;
  row[t + 256] = e1 * inv;
}

// in-place log_softmax over V=32000 per row; grid 2048, 256 thr (125 elems each)
__global__ void log_softmax_kernel(float* __restrict__ out) {
  __shared__ float sm[4];
  int m = blockIdx.x, t = threadIdx.x;
  float* row = out + (size_t)m * 32000u;
  float mx = NEG_INF;
  for (int j = t; j < 32000; j += 256) mx = fmaxf(mx, row[j]);
  mx = bred_max(mx, sm);
  float s = 0.f;
  for (int j = t; j < 32000; j += 256) s += expf(row[j] - mx);
  s = bred_sum(s, sm);
  float lse = mx + logf(s);
  for (int j = t; j < 32000; j += 256) row[j] -= lse;
}

// ---------------------------------------------------------------------------
// host driver
// ---------------------------------------------------------------------------
extern "C" void kernel_launch(void* const* d_in, const int* in_sizes, int n_in,
                              void* d_out, int out_size, void* d_ws, size_t ws_size,
                              hipStream_t stream) {
  const float* enc_out = (const float*)d_in[0];
  const int*   dec_in  = (const int*)d_in[1];
  const int*   enc_in  = (const int*)d_in[2];
  const float* emb     = (const float*)d_in[3];
  const float* wq1 = (const float*)d_in[4];  const float* bq1 = (const float*)d_in[5];
  const float* wk1 = (const float*)d_in[6];  const float* bk1 = (const float*)d_in[7];
  const float* wv1 = (const float*)d_in[8];  const float* bv1 = (const float*)d_in[9];
  const float* wo1 = (const float*)d_in[10]; const float* bo1 = (const float*)d_in[11];
  const float* pos1 = (const float*)d_in[12];
  const float* wq2 = (const float*)d_in[13]; const float* bq2 = (const float*)d_in[14];
  const float* wk2 = (const float*)d_in[15]; const float* bk2 = (const float*)d_in[16];
  const float* wv2 = (const float*)d_in[17]; const float* bv2 = (const float*)d_in[18];
  const float* wo2 = (const float*)d_in[19]; const float* bo2 = (const float*)d_in[20];
  const float* ln1g = (const float*)d_in[21]; const float* ln1b = (const float*)d_in[22];
  const float* ln2g = (const float*)d_in[23]; const float* ln2b = (const float*)d_in[24];
  const float* ln3g = (const float*)d_in[25]; const float* ln3b = (const float*)d_in[26];
  const float* wf1 = (const float*)d_in[27]; const float* bf1 = (const float*)d_in[28];
  const float* wf2 = (const float*)d_in[29]; const float* bf2 = (const float*)d_in[30];
  const float* wout = (const float*)d_in[31]; const float* bout = (const float*)d_in[32];

  float* W  = (float*)d_ws;
  float* X   = W;               // [2048,1024] layer input / LN3 out
  float* Xa  = X  + 2097152;    // x1
  float* Xb  = Xa + 2097152;    // x2
  float* Rb  = Xb + 2097152;    // pre-LN residual sums
  float* Q   = Rb + 2097152;    // [b,h,s,d]
  float* KT  = Q  + 2097152;    // [b,h,d,s]
  float* Vb  = KT + 2097152;    // [b,h,s,d]
  float* O   = Vb + 2097152;    // merged attn out [2048,1024]
  float* PT  = O  + 2097152;    // [64,512]
  float* PE  = PT + 32768;      // [32768,512]
  float* SC  = PE + 16777216;   // [64,512,512]  (also reused as FFN hidden)
  float* FFH = SC;              // [2048,4096]
  float* out = (float*)d_out;

  embed_kernel<<<2048, 256, 0, stream>>>(dec_in, emb, X);

  for (int i = 0; i < 6; ++i) {
    const size_t oHH = (size_t)i * 1048576u, oH = (size_t)i * 1024u;
    const float* wq1i = wq1 + oHH; const float* bq1i = bq1 + oH;
    const float* wk1i = wk1 + oHH; const float* bk1i = bk1 + oH;
    const float* wv1i = wv1 + oHH; const float* bv1i = bv1 + oH;
    const float* wo1i = wo1 + oHH; const float* bo1i = bo1 + oH;
    const float* posi = pos1 + (size_t)i * 65472u;  // 1023*64
    const float* wq2i = wq2 + oHH; const float* bq2i = bq2 + oH;
    const float* wk2i = wk2 + oHH; const float* bk2i = bk2 + oH;
    const float* wv2i = wv2 + oHH; const float* bv2i = bv2 + oH;
    const float* wo2i = wo2 + oHH; const float* bo2i = bo2 + oH;
    const float* wf1i = wf1 + (size_t)i * 4194304u; const float* bf1i = bf1 + (size_t)i * 4096u;
    const float* wf2i = wf2 + (size_t)i * 4194304u; const float* bf2i = bf2 + oH;

    // ---- self attention ----
    gemm_kernel<1,false,false><<<dim3(8,16,1),256,0,stream>>>(
        X,1024,0, wq1i,1024,0, bq1i, nullptr, Q,0,0, 2048,1024,1024, 0.125f);
    gemm_kernel<2,false,false><<<dim3(8,16,1),256,0,stream>>>(
        X,1024,0, wk1i,1024,0, bk1i, nullptr, KT,0,0, 2048,1024,1024, 1.f);
    gemm_kernel<1,false,false><<<dim3(8,16,1),256,0,stream>>>(
        X,1024,0, wv1i,1024,0, bv1i, nullptr, Vb,0,0, 2048,1024,1024, 1.f);
    transpose_pos<<<128,256,0,stream>>>(posi, PT);
    // PE = Qflat[32768,64] @ PT[64,512]
    gemm_kernel<0,false,false><<<dim3(4,256,1),256,0,stream>>>(
        Q,64,0, PT,512,0, nullptr, nullptr, PE,512,0, 32768,512,64, 1.f);
    // SC = Q @ K^T, batched over 64 (b,h)
    gemm_kernel<0,false,false><<<dim3(4,4,64),256,0,stream>>>(
        Q,64,32768, KT,512,32768, nullptr, nullptr, SC,512,262144, 512,512,64, 1.f);
    softmax_self<<<dim3(512,64),256,0,stream>>>(SC, PE, dec_in);
    // O = P @ V  (merge heads in epilogue)
    gemm_kernel<3,false,false><<<dim3(1,4,64),256,0,stream>>>(
        SC,512,262144, Vb,64,32768, nullptr, nullptr, O,0,0, 512,64,512, 1.f);
    // Rb = O @ wo1 + bo1 + X
    gemm_kernel<0,false,true><<<dim3(8,16,1),256,0,stream>>>(
        O,1024,0, wo1i,1024,0, bo1i, X, Rb,1024,0, 2048,1024,1024, 1.f);
    layernorm_kernel<<<2048,256,0,stream>>>(Rb, ln1g + oH, ln1b + oH, Xa);

    // ---- cross attention ----
    gemm_kernel<1,false,false><<<dim3(8,16,1),256,0,stream>>>(
        Xa,1024,0, wq2i,1024,0, bq2i, nullptr, Q,0,0, 2048,1024,1024, 0.125f);
    gemm_kernel<2,false,false><<<dim3(8,16,1),256,0,stream>>>(
        enc_out,1024,0, wk2i,1024,0, bk2i, nullptr, KT,0,0, 2048,1024,1024, 1.f);
    gemm_kernel<1,false,false><<<dim3(8,16,1),256,0,stream>>>(
        enc_out,1024,0, wv2i,1024,0, bv2i, nullptr, Vb,0,0, 2048,1024,1024, 1.f);
    gemm_kernel<0,false,false><<<dim3(4,4,64),256,0,stream>>>(
        Q,64,32768, KT,512,32768, nullptr, nullptr, SC,512,262144, 512,512,64, 1.f);
    softmax_cross<<<dim3(512,64),256,0,stream>>>(SC, enc_in);
    gemm_kernel<3,false,false><<<dim3(1,4,64),256,0,stream>>>(
        SC,512,262144, Vb,64,32768, nullptr, nullptr, O,0,0, 512,64,512, 1.f);
    gemm_kernel<0,false,true><<<dim3(8,16,1),256,0,stream>>>(
        O,1024,0, wo2i,1024,0, bo2i, Xa, Rb,1024,0, 2048,1024,1024, 1.f);
    layernorm_kernel<<<2048,256,0,stream>>>(Rb, ln2g + oH, ln2b + oH, Xb);

    // ---- FFN ----
    gemm_kernel<0,true,false><<<dim3(32,16,1),256,0,stream>>>(
        Xb,1024,0, wf1i,4096,0, bf1i, nullptr, FFH,4096,0, 2048,4096,1024, 1.f);
    gemm_kernel<0,false,true><<<dim3(8,16,1),256,0,stream>>>(
        FFH,4096,0, wf2i,1024,0, bf2i, Xb, Rb,1024,0, 2048,1024,4096, 1.f);
    layernorm_kernel<<<2048,256,0,stream>>>(Rb, ln3g + oH, ln3b + oH, X);
  }

  // ---- output head + log_softmax ----
  gemm_kernel<0,false,false><<<dim3(250,16,1),256,0,stream>>>(
      X,1024,0, wout,32000,0, bout, nullptr, out,32000,0, 2048,32000,1024, 1.f);
  log_softmax_kernel<<<2048,256,0,stream>>>(out);
}

// Round 2
// 2675.171 us; speedup vs baseline: 2.6435x; 2.6435x over previous
//
#include <hip/hip_runtime.h>

// ---------------------------------------------------------------------------
// TransformerDecoder forward on MI355X (gfx950) — round 2.
// bf16 everywhere: weights pre-transposed+converted to [N,K] bf16 per layer,
// activations kept in bf16 copies, m97-style GEMM (global_load_lds width=16,
// XOR-swizzled LDS, 128x128 / 64x128 tiles, BK=64).
// ---------------------------------------------------------------------------

typedef unsigned short u16;
typedef short s16x8 __attribute__((ext_vector_type(8)));
typedef unsigned short u16x4 __attribute__((ext_vector_type(4)));
typedef float f32x4 __attribute__((ext_vector_type(4)));

#define PADTOK 2
#define NEG_INF (-__builtin_inff())

static __device__ __forceinline__ u16 f2bf(float f) {
  unsigned u = __float_as_uint(f);
  u += 0x7fffu + ((u >> 16) & 1u);
  return (u16)(u >> 16);
}
static __device__ __forceinline__ float bf2f(u16 h) {
  return __uint_as_float(((unsigned)h) << 16);
}
static __device__ __forceinline__ f32x4 mfma16(s16x8 a, s16x8 b, f32x4 c) {
  asm("v_mfma_f32_16x16x32_bf16 %0, %1, %2, %0" : "+v"(c) : "v"(a), "v"(b));
  return c;
}
static __device__ __forceinline__ void gll16(const void* g, void* l) {
  __builtin_amdgcn_global_load_lds((const __attribute__((address_space(1))) void*)g,
                                   (__attribute__((address_space(3))) void*)l, 16, 0, 0);
}
static __device__ __forceinline__ size_t hsidx(int m, int n) {
  return ((size_t)((m >> 9) * 16 + (n >> 6))) * 32768u + (size_t)(m & 511) * 64u + (size_t)(n & 63);
}
static __device__ __forceinline__ size_t vtidx(int m, int n) {
  return ((size_t)((m >> 9) * 16 + (n >> 6))) * 65536u + (size_t)(n & 63) * 512u + (size_t)(m & 511);
}

// ---------------------------------------------------------------------------
// bf16 GEMM: C = epi(A[M,K] @ Bt[N,K]^T) per batch g. BM=MFR*32, BN=128, BK=64.
// A,Bt bf16 row-major, lda=ldb=K. global_load_lds staging, XOR swizzle.
// EPI: 0 plain  1 headsplit[g][s][d]  3 head-merge(n<64)  4 QKV-fused  5 KV-fused
// ---------------------------------------------------------------------------
template<int EPI, bool BF16OUT, int MFR, bool RELU, bool RESID>
__global__ __launch_bounds__(256)
void bgemm(const u16* __restrict__ A, long long sAg,
           const u16* __restrict__ Bt, long long sBg,
           const float* __restrict__ bias, const float* __restrict__ bias2,
           const float* __restrict__ bias3,
           const float* __restrict__ Res,
           void* __restrict__ Cv, u16* __restrict__ C2, u16* __restrict__ C3,
           long long sCg, int ldc, int K, float scale)
{
  constexpr int BM = MFR * 32;
  __shared__ u16 As[BM * 64];
  __shared__ u16 Bs[128 * 64];
  const int g = blockIdx.z;
  const u16* Ag = A + (size_t)g * (size_t)sAg;
  const u16* Bg = Bt + (size_t)g * (size_t)sBg;
  const int bm0 = blockIdx.y * BM, bn0 = blockIdx.x * 128;
  const int tid = threadIdx.x, l = tid & 63, w = tid >> 6;
  const int wm = w >> 1, wn = w & 1;
  const int rsel = l & 15, kg = l >> 4, xs = l & 7;

  f32x4 acc[MFR][4];
#pragma unroll
  for (int i = 0; i < MFR; ++i)
#pragma unroll
    for (int j = 0; j < 4; ++j) acc[i][j] = (f32x4){0.f, 0.f, 0.f, 0.f};

  // staging: per issue, 64 lanes x 16B = 8 rows of 64 bf16. Source chunk is
  // XOR-swizzled so reads can be conflict-free with a LINEAR LDS dest.
  const int srow = l >> 3;               // row within 8-row group
  const int sch  = (l & 7) ^ srow;       // swizzled source chunk
  const u16* Agp = Ag + ((size_t)(bm0 + w * 8 * MFR + srow)) * (size_t)K + sch * 8;
  const u16* Bgp = Bg + ((size_t)(bn0 + w * 32 + srow)) * (size_t)K + sch * 8;
  char* AsL = (char*)As + (w * 8 * MFR) * 128;
  char* BsL = (char*)Bs + (w * 32) * 128;

  for (int k0 = 0; k0 < K; k0 += 64) {
    __syncthreads();
#pragma unroll
    for (int i = 0; i < MFR; ++i)
      gll16(Agp + (size_t)i * 8 * K + k0, AsL + i * 1024);
#pragma unroll
    for (int i = 0; i < 4; ++i)
      gll16(Bgp + (size_t)i * 8 * K + k0, BsL + i * 1024);
    __syncthreads();

    const int arow0 = (wm * (MFR * 16) + rsel) * 128;
    const int brow0 = (wn * 64 + rsel) * 128;
#pragma unroll
    for (int ks = 0; ks < 2; ++ks) {
      const int ch = ((ks * 4 + kg) ^ xs) * 16;
      s16x8 af[MFR], bfr[4];
#pragma unroll
      for (int mf = 0; mf < MFR; ++mf)
        af[mf] = *(const s16x8*)((const char*)As + arow0 + mf * 2048 + ch);
#pragma unroll
      for (int nf = 0; nf < 4; ++nf)
        bfr[nf] = *(const s16x8*)((const char*)Bs + brow0 + nf * 2048 + ch);
#pragma unroll
      for (int mf = 0; mf < MFR; ++mf)
#pragma unroll
        for (int nf = 0; nf < 4; ++nf)
          acc[mf][nf] = mfma16(af[mf], bfr[nf], acc[mf][nf]);
    }
  }

  // epilogue: C/D layout col=lane&15 (n), row=(lane>>4)*4+e (m)
#pragma unroll
  for (int mf = 0; mf < MFR; ++mf) {
#pragma unroll
    for (int nf = 0; nf < 4; ++nf) {
      const int n = bn0 + wn * 64 + nf * 16 + rsel;
      if constexpr (EPI == 3) { if (n >= 64) continue; }
      int sub = 0, nl = n;
      const float* bp = bias;
      if constexpr (EPI == 4) {
        sub = n >> 10; nl = n & 1023;
        bp = (sub == 0) ? bias : (sub == 1) ? bias2 : bias3;
      }
      if constexpr (EPI == 5) {
        sub = n >> 10; nl = n & 1023;
        bp = (sub == 0) ? bias : bias2;
      }
      const float bv = bp ? bp[nl] : 0.f;
      float sc = 1.f;
      if constexpr (EPI == 0 || EPI == 1) sc = scale;
      if constexpr (EPI == 4) sc = (sub == 0) ? scale : 1.f;
#pragma unroll
      for (int e = 0; e < 4; ++e) {
        const int m = bm0 + wm * (MFR * 16) + mf * 16 + kg * 4 + e;
        float v = (acc[mf][nf][e] + bv) * sc;
        if constexpr (RELU) v = fmaxf(v, 0.f);
        if constexpr (RESID) v += Res[(size_t)m * (size_t)ldc + n];
        if constexpr (EPI == 0) {
          const size_t idx = (size_t)g * (size_t)sCg + (size_t)m * (size_t)ldc + n;
          if constexpr (BF16OUT) ((u16*)Cv)[idx] = f2bf(v);
          else                   ((float*)Cv)[idx] = v;
        } else if constexpr (EPI == 1) {
          ((u16*)Cv)[hsidx(m, nl)] = f2bf(v);
        } else if constexpr (EPI == 3) {
          const size_t idx = (size_t)(g >> 4) * 524288u + (size_t)m * 1024u
                           + (size_t)(g & 15) * 64u + n;
          ((u16*)Cv)[idx] = f2bf(v);
        } else if constexpr (EPI == 4) {
          if (sub == 2)      C3[vtidx(m, nl)] = f2bf(v);
          else if (sub == 1) C2[hsidx(m, nl)] = f2bf(v);
          else               ((u16*)Cv)[hsidx(m, nl)] = f2bf(v);
        } else if constexpr (EPI == 5) {
          if (sub == 0) ((u16*)Cv)[hsidx(m, nl)] = f2bf(v);
          else          C2[vtidx(m, nl)] = f2bf(v);
        }
      }
    }
  }
}

// ---------------------------------------------------------------------------
// transpose+convert f32[K,N] -> bf16[N,K], 64x64 tiles
// ---------------------------------------------------------------------------
static __device__ __forceinline__ void tconv_tile(const float* in, int N,
                                                  u16* out, int K, int k0, int n0) {
  __shared__ u16 L[64][72];
  const int t = threadIdx.x;
  const int rk = t >> 4, cn = (t & 15) * 4;
#pragma unroll
  for (int q = 0; q < 4; ++q) {
    const int kk = k0 + rk + q * 16;
    float4 v = *(const float4*)(in + (size_t)kk * (size_t)N + n0 + cn);
    L[cn + 0][rk + q * 16] = f2bf(v.x);
    L[cn + 1][rk + q * 16] = f2bf(v.y);
    L[cn + 2][rk + q * 16] = f2bf(v.z);
    L[cn + 3][rk + q * 16] = f2bf(v.w);
  }
  __syncthreads();
  const int rn = t >> 2, ck = (t & 3) * 16;
  u16* op = out + (size_t)(n0 + rn) * (size_t)K + k0 + ck;
  *(s16x8*)op       = *(const s16x8*)&L[rn][ck];
  *(s16x8*)(op + 8) = *(const s16x8*)&L[rn][ck + 8];
}

__global__ __launch_bounds__(256)
void conv_layer(const float* w0, const float* w1, const float* w2, const float* w3,
                const float* w4, const float* w5, const float* w6, const float* w7,
                const float* w8, const float* w9, u16* WT) {
  const int b = blockIdx.x;
  const float* in; u16* out; int N, K, kt, nt;
  if (b < 2048) {
    const int j = b >> 8, t = b & 255;
    const float* ws[8] = {w0, w1, w2, w3, w4, w5, w6, w7};
    in = ws[j]; out = WT + (size_t)j * 1048576u; K = 1024; N = 1024;
    kt = t >> 4; nt = t & 15;
  } else if (b < 3072) {
    const int t = b - 2048;
    in = w8; out = WT + 8388608u; K = 1024; N = 4096; kt = t >> 6; nt = t & 63;
  } else {
    const int t = b - 3072;
    in = w9; out = WT + 12582912u; K = 4096; N = 1024; kt = t >> 4; nt = t & 15;
  }
  tconv_tile(in, N, out, K, kt * 64, nt * 64);
}

__global__ __launch_bounds__(256)
void conv_wout(const float* in, u16* out) {
  const int b = blockIdx.x;            // 8000 = 16 ktiles * 500 ntiles
  const int kt = b / 500, nt = b % 500;
  tconv_tile(in, 32000, out, 1024, kt * 64, nt * 64);
}

// ---------------------------------------------------------------------------
// elementwise converts
// ---------------------------------------------------------------------------
__global__ void conv_bf16(const float* __restrict__ in, u16* __restrict__ out) {
  const int i = (blockIdx.x * 256 + threadIdx.x) * 4;
  float4 v = *(const float4*)(in + i);
  u16x4 h = {f2bf(v.x), f2bf(v.y), f2bf(v.z), f2bf(v.w)};
  *(u16x4*)(out + i) = h;
}

// pos1 layer slices [1023][64] -> posb [6][512][64] bf16 (rows 0..511)
__global__ void conv_pos(const float* __restrict__ pos, u16* __restrict__ posb) {
  const int idx = (blockIdx.x * 256 + threadIdx.x) * 4;   // over 6*512*64
  const int lyr = idx >> 15, rem = idx & 32767;
  float4 v = *(const float4*)(pos + (size_t)lyr * 65472u + rem);
  u16x4 h = {f2bf(v.x), f2bf(v.y), f2bf(v.z), f2bf(v.w)};
  *(u16x4*)(posb + idx) = h;
}

// ---------------------------------------------------------------------------
// reductions
// ---------------------------------------------------------------------------
static __device__ __forceinline__ float wred_sum(float v) {
#pragma unroll
  for (int o = 32; o > 0; o >>= 1) v += __shfl_down(v, o, 64);
  return v;
}
static __device__ __forceinline__ float wred_max(float v) {
#pragma unroll
  for (int o = 32; o > 0; o >>= 1) v = fmaxf(v, __shfl_down(v, o, 64));
  return v;
}
static __device__ __forceinline__ float bred_sum(float v, float* sm) {
  const int lane = threadIdx.x & 63, wid = threadIdx.x >> 6;
  v = wred_sum(v);
  if (lane == 0) sm[wid] = v;
  __syncthreads();
  if (threadIdx.x == 0) sm[0] = sm[0] + sm[1] + sm[2] + sm[3];
  __syncthreads();
  const float r = sm[0];
  __syncthreads();
  return r;
}
static __device__ __forceinline__ float bred_max(float v, float* sm) {
  const int lane = threadIdx.x & 63, wid = threadIdx.x >> 6;
  v = wred_max(v);
  if (lane == 0) sm[wid] = v;
  __syncthreads();
  if (threadIdx.x == 0) sm[0] = fmaxf(fmaxf(sm[0], sm[1]), fmaxf(sm[2], sm[3]));
  __syncthreads();
  const float r = sm[0];
  __syncthreads();
  return r;
}

// ---------------------------------------------------------------------------
// small kernels
// ---------------------------------------------------------------------------
__global__ void embed_kernel(const int* __restrict__ dec, const float* __restrict__ emb,
                             float* __restrict__ X, u16* __restrict__ Xh) {
  const int m = blockIdx.x, t = threadIdx.x;
  const int tok = dec[m];
  float4 v = ((const float4*)(emb + (size_t)tok * 1024u))[t];
  ((float4*)(X + (size_t)m * 1024u))[t] = v;
  u16x4 h = {f2bf(v.x), f2bf(v.y), f2bf(v.z), f2bf(v.w)};
  *(u16x4*)(Xh + (size_t)m * 1024u + t * 4) = h;
}

__global__ void layernorm_kernel(const float* __restrict__ R,
                                 const float* __restrict__ gw, const float* __restrict__ bw,
                                 float* __restrict__ Y, u16* __restrict__ Yh) {
  __shared__ float sm[4];
  const int m = blockIdx.x, t = threadIdx.x;
  float4 v = ((const float4*)(R + (size_t)m * 1024u))[t];
  float s = v.x + v.y + v.z + v.w;
  s = bred_sum(s, sm);
  const float mean = s * (1.f / 1024.f);
  const float d0 = v.x - mean, d1 = v.y - mean, d2 = v.z - mean, d3 = v.w - mean;
  float q = d0 * d0 + d1 * d1 + d2 * d2 + d3 * d3;
  q = bred_sum(q, sm);
  const float rstd = rsqrtf(q * (1.f / 1024.f) + 1e-5f);
  const int c = t * 4;
  float4 o;
  o.x = d0 * rstd * gw[c + 0] + bw[c + 0];
  o.y = d1 * rstd * gw[c + 1] + bw[c + 1];
  o.z = d2 * rstd * gw[c + 2] + bw[c + 2];
  o.w = d3 * rstd * gw[c + 3] + bw[c + 3];
  ((float4*)(Y + (size_t)m * 1024u))[t] = o;
  u16x4 h = {f2bf(o.x), f2bf(o.y), f2bf(o.z), f2bf(o.w)};
  *(u16x4*)(Yh + (size_t)m * 1024u + c) = h;
}

// self softmax: reads SC(bf16) + PE(bf16, in P buffer), writes P(bf16) in place of PE
__global__ void softmax_self(const u16* __restrict__ SC, u16* __restrict__ P,
                             const int* __restrict__ dec) {
  __shared__ float sm[4];
  const int i = blockIdx.x, gq = blockIdx.y, b = gq >> 4, t = threadIdx.x;
  const u16* row = SC + ((size_t)(gq * 512 + i)) * 512u;
  u16* prow = P + ((size_t)(gq * 512 + i)) * 512u;
  float v0, v1;
  {
    int j = t;
    bool ok = (j <= i) && (dec[b * 512 + j] != PADTOK);
    int r = ok ? (511 + j - i) : 0;
    v0 = ok ? (bf2f(row[j]) + bf2f(prow[r])) : NEG_INF;
    j = t + 256;
    ok = (j <= i) && (dec[b * 512 + j] != PADTOK);
    r = ok ? (511 + j - i) : 0;
    v1 = ok ? (bf2f(row[j]) + bf2f(prow[r])) : NEG_INF;
  }
  const float mx = bred_max(fmaxf(v0, v1), sm);       // barrier: all PE reads done
  const float e0 = expf(v0 - mx), e1 = expf(v1 - mx);
  const float s = bred_sum(e0 + e1, sm);
  const float inv = 1.f / s;
  prow[t] = f2bf(e0 * inv);
  prow[t + 256] = f2bf(e1 * inv);
}

__global__ void softmax_cross(const u16* __restrict__ SC, u16* __restrict__ P,
                              const int* __restrict__ enc) {
  __shared__ float sm[4];
  const int i = blockIdx.x, gq = blockIdx.y, b = gq >> 4, t = threadIdx.x;
  const u16* row = SC + ((size_t)(gq * 512 + i)) * 512u;
  u16* prow = P + ((size_t)(gq * 512 + i)) * 512u;
  const float v0 = (enc[b * 512 + t] == PADTOK) ? NEG_INF : bf2f(row[t]);
  const float v1 = (enc[b * 512 + t + 256] == PADTOK) ? NEG_INF : bf2f(row[t + 256]);
  const float mx = bred_max(fmaxf(v0, v1), sm);
  const float e0 = expf(v0 - mx), e1 = expf(v1 - mx);
  const float s = bred_sum(e0 + e1, sm);
  const float inv = 1.f / s;
  prow[t] = f2bf(e0 * inv);
  prow[t + 256] = f2bf(e1 * inv);
}

__global__ void log_softmax_kernel(float* __restrict__ out) {
  __shared__ float sm[4];
  const int m = blockIdx.x, t = threadIdx.x;
  float* row = out + (size_t)m * 32000u;
  float mx = NEG_INF;
  for (int j = t; j < 32000; j += 256) mx = fmaxf(mx, row[j]);
  mx = bred_max(mx, sm);
  float s = 0.f;
  for (int j = t; j < 32000; j += 256) s += expf(row[j] - mx);
  s = bred_sum(s, sm);
  const float lse = mx + logf(s);
  for (int j = t; j < 32000; j += 256) row[j] -= lse;
}

// ---------------------------------------------------------------------------
// host driver
// ---------------------------------------------------------------------------
extern "C" void kernel_launch(void* const* d_in, const int* in_sizes, int n_in,
                              void* d_out, int out_size, void* d_ws, size_t ws_size,
                              hipStream_t stream) {
  const float* enc_out = (const float*)d_in[0];
  const int*   dec_in  = (const int*)d_in[1];
  const int*   enc_in  = (const int*)d_in[2];
  const float* emb     = (const float*)d_in[3];
  const float* wq1 = (const float*)d_in[4];  const float* bq1 = (const float*)d_in[5];
  const float* wk1 = (const float*)d_in[6];  const float* bk1 = (const float*)d_in[7];
  const float* wv1 = (const float*)d_in[8];  const float* bv1 = (const float*)d_in[9];
  const float* wo1 = (const float*)d_in[10]; const float* bo1 = (const float*)d_in[11];
  const float* pos1 = (const float*)d_in[12];
  const float* wq2 = (const float*)d_in[13]; const float* bq2 = (const float*)d_in[14];
  const float* wk2 = (const float*)d_in[15]; const float* bk2 = (const float*)d_in[16];
  const float* wv2 = (const float*)d_in[17]; const float* bv2 = (const float*)d_in[18];
  const float* wo2 = (const float*)d_in[19]; const float* bo2 = (const float*)d_in[20];
  const float* ln1g = (const float*)d_in[21]; const float* ln1b = (const float*)d_in[22];
  const float* ln2g = (const float*)d_in[23]; const float* ln2b = (const float*)d_in[24];
  const float* ln3g = (const float*)d_in[25]; const float* ln3b = (const float*)d_in[26];
  const float* wf1 = (const float*)d_in[27]; const float* bf1 = (const float*)d_in[28];
  const float* wf2 = (const float*)d_in[29]; const float* bf2 = (const float*)d_in[30];
  const float* wout = (const float*)d_in[31]; const float* bout = (const float*)d_in[32];

  char* ws = (char*)d_ws;
  u16*   WT    = (u16*)(ws + 0);             // 32MB  (per-layer transposed weights)
  u16*   SCb   = (u16*)(ws + 33554432);      // 32MB  scores bf16 [64][512][512]
  u16*   WoutT = (u16*)(ws + 0);             // 65.5MB, overlaps WT+SCb (used at end)
  u16*   PEP   = (u16*)(ws + 67108864);      // 32MB  PE / P bf16 [32768][512]
  float* X     = (float*)(ws + 100663296);   // 8MB
  float* Xa    = (float*)(ws + 109051904);   // 8MB
  float* Xb    = (float*)(ws + 117440512);   // 8MB
  float* Rb    = (float*)(ws + 125829120);   // 8MB
  u16*   Ab16  = (u16*)(ws + 134217728);     // 4MB  current GEMM-input activation
  u16*   Q     = (u16*)(ws + 138412032);     // 4MB  [g][512][64]
  u16*   Kh    = (u16*)(ws + 142606336);     // 4MB  [g][512][64]
  u16*   VT    = (u16*)(ws + 146800640);     // 8MB  [g][128(pad)][512]
  u16*   Ob16  = (u16*)(ws + 155189248);     // 4MB  merged attn out
  u16*   FFH16 = (u16*)(ws + 159383552);     // 16MB [2048][4096]
  u16*   encb  = (u16*)(ws + 176160768);     // 4MB  encoder_outputs bf16
  u16*   posb  = (u16*)(ws + 180355072);     // 384KB [6][512][64]
  float* out   = (float*)d_out;

  embed_kernel<<<2048, 256, 0, stream>>>(dec_in, emb, X, Ab16);
  conv_bf16<<<2048, 256, 0, stream>>>(enc_out, encb);
  conv_pos<<<192, 256, 0, stream>>>(pos1, posb);

  for (int i = 0; i < 6; ++i) {
    const size_t oHH = (size_t)i * 1048576u, oH = (size_t)i * 1024u;
    const float* bq1i = bq1 + oH; const float* bk1i = bk1 + oH;
    const float* bv1i = bv1 + oH; const float* bo1i = bo1 + oH;
    const float* bq2i = bq2 + oH; const float* bk2i = bk2 + oH;
    const float* bv2i = bv2 + oH; const float* bo2i = bo2 + oH;
    const float* bf1i = bf1 + (size_t)i * 4096u; const float* bf2i = bf2 + oH;
    const u16* posL = posb + (size_t)i * 32768u;

    conv_layer<<<4096, 256, 0, stream>>>(
        wq1 + oHH, wk1 + oHH, wv1 + oHH, wo1 + oHH,
        wq2 + oHH, wk2 + oHH, wv2 + oHH, wo2 + oHH,
        wf1 + (size_t)i * 4194304u, wf2 + (size_t)i * 4194304u, WT);

    // ---- self attention ----
    bgemm<4, true, 4, false, false><<<dim3(24, 16, 1), 256, 0, stream>>>(
        Ab16, 0, WT, 0, bq1i, bk1i, bv1i, nullptr, Q, Kh, VT, 0, 0, 1024, 0.125f);
    bgemm<0, true, 4, false, false><<<dim3(4, 256, 1), 256, 0, stream>>>(
        Q, 0, posL, 0, nullptr, nullptr, nullptr, nullptr, PEP, nullptr, nullptr,
        0, 512, 64, 1.f);
    bgemm<0, true, 4, false, false><<<dim3(4, 4, 64), 256, 0, stream>>>(
        Q, 32768, Kh, 32768, nullptr, nullptr, nullptr, nullptr, SCb, nullptr, nullptr,
        262144, 512, 64, 1.f);
    softmax_self<<<dim3(512, 64), 256, 0, stream>>>(SCb, PEP, dec_in);
    bgemm<3, true, 4, false, false><<<dim3(1, 4, 64), 256, 0, stream>>>(
        PEP, 262144, VT, 65536, nullptr, nullptr, nullptr, nullptr, Ob16, nullptr, nullptr,
        0, 0, 512, 1.f);
    bgemm<0, false, 2, false, true><<<dim3(8, 32, 1), 256, 0, stream>>>(
        Ob16, 0, WT + 3145728u, 0, bo1i, nullptr, nullptr, X, Rb, nullptr, nullptr,
        0, 1024, 1024, 1.f);
    layernorm_kernel<<<2048, 256, 0, stream>>>(Rb, ln1g + oH, ln1b + oH, Xa, Ab16);

    // ---- cross attention ----
    bgemm<1, true, 2, false, false><<<dim3(8, 32, 1), 256, 0, stream>>>(
        Ab16, 0, WT + 4194304u, 0, bq2i, nullptr, nullptr, nullptr, Q, nullptr, nullptr,
        0, 0, 1024, 0.125f);
    bgemm<5, true, 4, false, false><<<dim3(16, 16, 1), 256, 0, stream>>>(
        encb, 0, WT + 5242880u, 0, bk2i, bv2i, nullptr, nullptr, Kh, VT, nullptr,
        0, 0, 1024, 1.f);
    bgemm<0, true, 4, false, false><<<dim3(4, 4, 64), 256, 0, stream>>>(
        Q, 32768, Kh, 32768, nullptr, nullptr, nullptr, nullptr, SCb, nullptr, nullptr,
        262144, 512, 64, 1.f);
    softmax_cross<<<dim3(512, 64), 256, 0, stream>>>(SCb, PEP, enc_in);
    bgemm<3, true, 4, false, false><<<dim3(1, 4, 64), 256, 0, stream>>>(
        PEP, 262144, VT, 65536, nullptr, nullptr, nullptr, nullptr, Ob16, nullptr, nullptr,
        0, 0, 512, 1.f);
    bgemm<0, false, 2, false, true><<<dim3(8, 32, 1), 256, 0, stream>>>(
        Ob16, 0, WT + 7340032u, 0, bo2i, nullptr, nullptr, Xa, Rb, nullptr, nullptr,
        0, 1024, 1024, 1.f);
    layernorm_kernel<<<2048, 256, 0, stream>>>(Rb, ln2g + oH, ln2b + oH, Xb, Ab16);

    // ---- FFN ----
    bgemm<0, true, 4, true, false><<<dim3(32, 16, 1), 256, 0, stream>>>(
        Ab16, 0, WT + 8388608u, 0, bf1i, nullptr, nullptr, nullptr, FFH16, nullptr, nullptr,
        0, 4096, 1024, 1.f);
    bgemm<0, false, 2, false, true><<<dim3(8, 32, 1), 256, 0, stream>>>(
        FFH16, 0, WT + 12582912u, 0, bf2i, nullptr, nullptr, Xb, Rb, nullptr, nullptr,
        0, 1024, 4096, 1.f);
    layernorm_kernel<<<2048, 256, 0, stream>>>(Rb, ln3g + oH, ln3b + oH, X, Ab16);
  }

  // ---- output head + log_softmax ----
  conv_wout<<<8000, 256, 0, stream>>>(wout, WoutT);
  bgemm<0, false, 4, false, false><<<dim3(250, 16, 1), 256, 0, stream>>>(
      Ab16, 0, WoutT, 0, bout, nullptr, nullptr, nullptr, out, nullptr, nullptr,
      0, 32000, 1024, 1.f);
  log_softmax_kernel<<<2048, 256, 0, stream>>>(out);
}

// Round 3
// 2349.500 us; speedup vs baseline: 3.0100x; 1.1386x over previous
//
#include <hip/hip_runtime.h>

// ---------------------------------------------------------------------------
// TransformerDecoder forward on MI355X (gfx950) — round 3.
// Round-3 deltas: XCD-swizzled m-grouped rasterization in bgemm, f16 logits
// (d_out used as staging), LDS-staged vectorized log-softmax, vectorized
// 2-row softmax kernels, causal block-skip in self-attn scores GEMM.
// ---------------------------------------------------------------------------

typedef unsigned short u16;
typedef short s16x8 __attribute__((ext_vector_type(8)));
typedef unsigned short u16x4 __attribute__((ext_vector_type(4)));
typedef unsigned short u16x8 __attribute__((ext_vector_type(8)));
typedef float f32x4 __attribute__((ext_vector_type(4)));

#define PADTOK 2
#define NEG_INF (-__builtin_inff())

static __device__ __forceinline__ u16 f2bf(float f) {
  unsigned u = __float_as_uint(f);
  u += 0x7fffu + ((u >> 16) & 1u);
  return (u16)(u >> 16);
}
static __device__ __forceinline__ float bf2f(u16 h) {
  return __uint_as_float(((unsigned)h) << 16);
}
static __device__ __forceinline__ float f16tof(u16 h) {
  _Float16 x = __builtin_bit_cast(_Float16, h);
  return (float)x;
}
static __device__ __forceinline__ u16 ftof16(float v) {
  _Float16 x = (_Float16)v;
  return __builtin_bit_cast(u16, x);
}
static __device__ __forceinline__ f32x4 mfma16(s16x8 a, s16x8 b, f32x4 c) {
  asm("v_mfma_f32_16x16x32_bf16 %0, %1, %2, %0" : "+v"(c) : "v"(a), "v"(b));
  return c;
}
static __device__ __forceinline__ void gll16(const void* g, void* l) {
  __builtin_amdgcn_global_load_lds((const __attribute__((address_space(1))) void*)g,
                                   (__attribute__((address_space(3))) void*)l, 16, 0, 0);
}
static __device__ __forceinline__ size_t hsidx(int m, int n) {
  return ((size_t)((m >> 9) * 16 + (n >> 6))) * 32768u + (size_t)(m & 511) * 64u + (size_t)(n & 63);
}
static __device__ __forceinline__ size_t vtidx(int m, int n) {
  return ((size_t)((m >> 9) * 16 + (n >> 6))) * 65536u + (size_t)(n & 63) * 512u + (size_t)(m & 511);
}

// XCD-chunked (bijective) + m-grouped (GM=8) n-major rasterization.
static __device__ __forceinline__ void raster2(int& bm, int& bn) {
  const int nm = gridDim.y, nn = gridDim.x;
  int bid = blockIdx.y * nn + blockIdx.x;
  const int nwg = nm * nn;
  const int q = nwg >> 3, r = nwg & 7;
  const int x = bid & 7, p = bid >> 3;
  bid = (x < r ? x * (q + 1) : r * (q + 1) + (x - r) * q) + p;
  const int GM = nm < 8 ? nm : 8;
  const int pg = GM * nn;
  const int gi = bid / pg, rem = bid - gi * pg;
  const int left = nm - gi * GM;
  const int gm = left < GM ? left : GM;
  bm = gi * GM + rem % gm;
  bn = rem / gm;
}

// ---------------------------------------------------------------------------
// bf16 GEMM: C = epi(A[M,K] @ Bt[N,K]^T) per batch g. BM=MFR*32, BN=128, BK=64.
// EPI: 0 plain  1 headsplit  3 head-merge(n<64)  4 QKV-fused  5 KV-fused
//      6 f16 out (ldc in u16 units)
// ---------------------------------------------------------------------------
template<int EPI, bool BF16OUT, int MFR, bool RELU, bool RESID, bool CSKIP>
__global__ __launch_bounds__(256)
void bgemm(const u16* __restrict__ A, long long sAg,
           const u16* __restrict__ Bt, long long sBg,
           const float* __restrict__ bias, const float* __restrict__ bias2,
           const float* __restrict__ bias3,
           const float* __restrict__ Res,
           void* __restrict__ Cv, u16* __restrict__ C2, u16* __restrict__ C3,
           long long sCg, int ldc, int K, float scale)
{
  constexpr int BM = MFR * 32;
  __shared__ u16 As[BM * 64];
  __shared__ u16 Bs[128 * 64];
  int bmi, bni;
  raster2(bmi, bni);
  const int bm0 = bmi * BM, bn0 = bni * 128;
  if constexpr (CSKIP) {           // causal: whole tile strictly above diagonal
    if (bn0 > bm0 + BM - 1) return;
  }
  const int g = blockIdx.z;
  const u16* Ag = A + (size_t)g * (size_t)sAg;
  const u16* Bg = Bt + (size_t)g * (size_t)sBg;
  const int tid = threadIdx.x, l = tid & 63, w = tid >> 6;
  const int wm = w >> 1, wn = w & 1;
  const int rsel = l & 15, kg = l >> 4, xs = l & 7;

  f32x4 acc[MFR][4];
#pragma unroll
  for (int i = 0; i < MFR; ++i)
#pragma unroll
    for (int j = 0; j < 4; ++j) acc[i][j] = (f32x4){0.f, 0.f, 0.f, 0.f};

  const int srow = l >> 3;               // row within 8-row group
  const int sch  = (l & 7) ^ srow;       // swizzled source chunk
  const u16* Agp = Ag + ((size_t)(bm0 + w * 8 * MFR + srow)) * (size_t)K + sch * 8;
  const u16* Bgp = Bg + ((size_t)(bn0 + w * 32 + srow)) * (size_t)K + sch * 8;
  char* AsL = (char*)As + (w * 8 * MFR) * 128;
  char* BsL = (char*)Bs + (w * 32) * 128;

  for (int k0 = 0; k0 < K; k0 += 64) {
    __syncthreads();
#pragma unroll
    for (int i = 0; i < MFR; ++i)
      gll16(Agp + (size_t)i * 8 * K + k0, AsL + i * 1024);
#pragma unroll
    for (int i = 0; i < 4; ++i)
      gll16(Bgp + (size_t)i * 8 * K + k0, BsL + i * 1024);
    __syncthreads();

    const int arow0 = (wm * (MFR * 16) + rsel) * 128;
    const int brow0 = (wn * 64 + rsel) * 128;
#pragma unroll
    for (int ks = 0; ks < 2; ++ks) {
      const int ch = ((ks * 4 + kg) ^ xs) * 16;
      s16x8 af[MFR], bfr[4];
#pragma unroll
      for (int mf = 0; mf < MFR; ++mf)
        af[mf] = *(const s16x8*)((const char*)As + arow0 + mf * 2048 + ch);
#pragma unroll
      for (int nf = 0; nf < 4; ++nf)
        bfr[nf] = *(const s16x8*)((const char*)Bs + brow0 + nf * 2048 + ch);
#pragma unroll
      for (int mf = 0; mf < MFR; ++mf)
#pragma unroll
        for (int nf = 0; nf < 4; ++nf)
          acc[mf][nf] = mfma16(af[mf], bfr[nf], acc[mf][nf]);
    }
  }

  // epilogue: C/D layout col=lane&15 (n), row=(lane>>4)*4+e (m)
#pragma unroll
  for (int mf = 0; mf < MFR; ++mf) {
#pragma unroll
    for (int nf = 0; nf < 4; ++nf) {
      const int n = bn0 + wn * 64 + nf * 16 + rsel;
      if constexpr (EPI == 3) { if (n >= 64) continue; }
      int sub = 0, nl = n;
      const float* bp = bias;
      if constexpr (EPI == 4) {
        sub = n >> 10; nl = n & 1023;
        bp = (sub == 0) ? bias : (sub == 1) ? bias2 : bias3;
      }
      if constexpr (EPI == 5) {
        sub = n >> 10; nl = n & 1023;
        bp = (sub == 0) ? bias : bias2;
      }
      const float bv = bp ? bp[nl] : 0.f;
      float sc = 1.f;
      if constexpr (EPI == 0 || EPI == 1) sc = scale;
      if constexpr (EPI == 4) sc = (sub == 0) ? scale : 1.f;
#pragma unroll
      for (int e = 0; e < 4; ++e) {
        const int m = bm0 + wm * (MFR * 16) + mf * 16 + kg * 4 + e;
        float v = (acc[mf][nf][e] + bv) * sc;
        if constexpr (RELU) v = fmaxf(v, 0.f);
        if constexpr (RESID) v += Res[(size_t)m * (size_t)ldc + n];
        if constexpr (EPI == 0) {
          const size_t idx = (size_t)g * (size_t)sCg + (size_t)m * (size_t)ldc + n;
          if constexpr (BF16OUT) ((u16*)Cv)[idx] = f2bf(v);
          else                   ((float*)Cv)[idx] = v;
        } else if constexpr (EPI == 1) {
          ((u16*)Cv)[hsidx(m, nl)] = f2bf(v);
        } else if constexpr (EPI == 3) {
          const size_t idx = (size_t)(g >> 4) * 524288u + (size_t)m * 1024u
                           + (size_t)(g & 15) * 64u + n;
          ((u16*)Cv)[idx] = f2bf(v);
        } else if constexpr (EPI == 4) {
          if (sub == 2)      C3[vtidx(m, nl)] = f2bf(v);
          else if (sub == 1) C2[hsidx(m, nl)] = f2bf(v);
          else               ((u16*)Cv)[hsidx(m, nl)] = f2bf(v);
        } else if constexpr (EPI == 5) {
          if (sub == 0) ((u16*)Cv)[hsidx(m, nl)] = f2bf(v);
          else          C2[vtidx(m, nl)] = f2bf(v);
        } else if constexpr (EPI == 6) {
          ((u16*)Cv)[(size_t)m * (size_t)ldc + n] = ftof16(v);
        }
      }
    }
  }
}

// ---------------------------------------------------------------------------
// transpose+convert f32[K,N] -> bf16[N,K], 64x64 tiles
// ---------------------------------------------------------------------------
static __device__ __forceinline__ void tconv_tile(const float* in, int N,
                                                  u16* out, int K, int k0, int n0) {
  __shared__ u16 L[64][72];
  const int t = threadIdx.x;
  const int rk = t >> 4, cn = (t & 15) * 4;
#pragma unroll
  for (int q = 0; q < 4; ++q) {
    const int kk = k0 + rk + q * 16;
    float4 v = *(const float4*)(in + (size_t)kk * (size_t)N + n0 + cn);
    L[cn + 0][rk + q * 16] = f2bf(v.x);
    L[cn + 1][rk + q * 16] = f2bf(v.y);
    L[cn + 2][rk + q * 16] = f2bf(v.z);
    L[cn + 3][rk + q * 16] = f2bf(v.w);
  }
  __syncthreads();
  const int rn = t >> 2, ck = (t & 3) * 16;
  u16* op = out + (size_t)(n0 + rn) * (size_t)K + k0 + ck;
  *(s16x8*)op       = *(const s16x8*)&L[rn][ck];
  *(s16x8*)(op + 8) = *(const s16x8*)&L[rn][ck + 8];
}

__global__ __launch_bounds__(256)
void conv_layer(const float* w0, const float* w1, const float* w2, const float* w3,
                const float* w4, const float* w5, const float* w6, const float* w7,
                const float* w8, const float* w9, u16* WT) {
  const int b = blockIdx.x;
  const float* in; u16* out; int N, K, kt, nt;
  if (b < 2048) {
    const int j = b >> 8, t = b & 255;
    const float* ws[8] = {w0, w1, w2, w3, w4, w5, w6, w7};
    in = ws[j]; out = WT + (size_t)j * 1048576u; K = 1024; N = 1024;
    kt = t >> 4; nt = t & 15;
  } else if (b < 3072) {
    const int t = b - 2048;
    in = w8; out = WT + 8388608u; K = 1024; N = 4096; kt = t >> 6; nt = t & 63;
  } else {
    const int t = b - 3072;
    in = w9; out = WT + 12582912u; K = 4096; N = 1024; kt = t >> 4; nt = t & 15;
  }
  tconv_tile(in, N, out, K, kt * 64, nt * 64);
}

__global__ __launch_bounds__(256)
void conv_wout(const float* in, u16* out) {
  const int b = blockIdx.x;            // 8000 = 16 ktiles * 500 ntiles
  const int kt = b / 500, nt = b % 500;
  tconv_tile(in, 32000, out, 1024, kt * 64, nt * 64);
}

// ---------------------------------------------------------------------------
// elementwise converts
// ---------------------------------------------------------------------------
__global__ void conv_bf16(const float* __restrict__ in, u16* __restrict__ out) {
  const int i = (blockIdx.x * 256 + threadIdx.x) * 4;
  float4 v = *(const float4*)(in + i);
  u16x4 h = {f2bf(v.x), f2bf(v.y), f2bf(v.z), f2bf(v.w)};
  *(u16x4*)(out + i) = h;
}

__global__ void conv_pos(const float* __restrict__ pos, u16* __restrict__ posb) {
  const int idx = (blockIdx.x * 256 + threadIdx.x) * 4;   // over 6*512*64
  const int lyr = idx >> 15, rem = idx & 32767;
  float4 v = *(const float4*)(pos + (size_t)lyr * 65472u + rem);
  u16x4 h = {f2bf(v.x), f2bf(v.y), f2bf(v.z), f2bf(v.w)};
  *(u16x4*)(posb + idx) = h;
}

// ---------------------------------------------------------------------------
// reductions
// ---------------------------------------------------------------------------
static __device__ __forceinline__ float wred_sum(float v) {
#pragma unroll
  for (int o = 32; o > 0; o >>= 1) v += __shfl_down(v, o, 64);
  return v;
}
static __device__ __forceinline__ float wred_max(float v) {
#pragma unroll
  for (int o = 32; o > 0; o >>= 1) v = fmaxf(v, __shfl_down(v, o, 64));
  return v;
}
static __device__ __forceinline__ float bred_sum(float v, float* sm) {
  const int lane = threadIdx.x & 63, wid = threadIdx.x >> 6;
  v = wred_sum(v);
  if (lane == 0) sm[wid] = v;
  __syncthreads();
  if (threadIdx.x == 0) sm[0] = sm[0] + sm[1] + sm[2] + sm[3];
  __syncthreads();
  const float r = sm[0];
  __syncthreads();
  return r;
}

// ---------------------------------------------------------------------------
// small kernels
// ---------------------------------------------------------------------------
__global__ void embed_kernel(const int* __restrict__ dec, const float* __restrict__ emb,
                             float* __restrict__ X, u16* __restrict__ Xh) {
  const int m = blockIdx.x, t = threadIdx.x;
  const int tok = dec[m];
  float4 v = ((const float4*)(emb + (size_t)tok * 1024u))[t];
  ((float4*)(X + (size_t)m * 1024u))[t] = v;
  u16x4 h = {f2bf(v.x), f2bf(v.y), f2bf(v.z), f2bf(v.w)};
  *(u16x4*)(Xh + (size_t)m * 1024u + t * 4) = h;
}

__global__ void layernorm_kernel(const float* __restrict__ R,
                                 const float* __restrict__ gw, const float* __restrict__ bw,
                                 float* __restrict__ Y, u16* __restrict__ Yh) {
  __shared__ float sm[4];
  const int m = blockIdx.x, t = threadIdx.x;
  float4 v = ((const float4*)(R + (size_t)m * 1024u))[t];
  float s = v.x + v.y + v.z + v.w;
  s = bred_sum(s, sm);
  const float mean = s * (1.f / 1024.f);
  const float d0 = v.x - mean, d1 = v.y - mean, d2 = v.z - mean, d3 = v.w - mean;
  float q = d0 * d0 + d1 * d1 + d2 * d2 + d3 * d3;
  q = bred_sum(q, sm);
  const float rstd = rsqrtf(q * (1.f / 1024.f) + 1e-5f);
  const int c = t * 4;
  float4 o;
  o.x = d0 * rstd * gw[c + 0] + bw[c + 0];
  o.y = d1 * rstd * gw[c + 1] + bw[c + 1];
  o.z = d2 * rstd * gw[c + 2] + bw[c + 2];
  o.w = d3 * rstd * gw[c + 3] + bw[c + 3];
  ((float4*)(Y + (size_t)m * 1024u))[t] = o;
  u16x4 h = {f2bf(o.x), f2bf(o.y), f2bf(o.z), f2bf(o.w)};
  *(u16x4*)(Yh + (size_t)m * 1024u + c) = h;
}

// vectorized softmax: 2 rows per 256-thread block; half-block (128 thr = 2
// waves) per row, 4 contiguous cols per thread.
// SELF: adds skew (PE lookup) + causal + pad mask; P written over PE buffer.
template<bool SELF>
__global__ void softmax_rows(const u16* __restrict__ SC, u16* __restrict__ P,
                             const int* __restrict__ msk) {
  __shared__ float sm[4];
  const int g = blockIdx.y, b = g >> 4;
  const int tid = threadIdx.x;
  const int half = tid >> 7, t = tid & 127, wid = tid >> 6;
  const int i = blockIdx.x * 2 + half;
  const size_t ro = ((size_t)g * 512 + (size_t)i) * 512u;
  const u16* row = SC + ro;
  u16* prow = P + ro;
  const int j0 = t * 4;
  const u16x4 sv = *(const u16x4*)(row + j0);
  const int4 dv = *(const int4*)(msk + b * 512 + j0);
  const int dm[4] = {dv.x, dv.y, dv.z, dv.w};
  float v[4];
#pragma unroll
  for (int e = 0; e < 4; ++e) {
    const int j = j0 + e;
    bool ok = (dm[e] != PADTOK);
    if constexpr (SELF) ok = ok && (j <= i);
    float x;
    if constexpr (SELF) {
      const int r = (j <= i) ? (511 + j - i) : 0;
      x = bf2f(sv[e]) + bf2f(prow[r]);
    } else {
      x = bf2f(sv[e]);
    }
    v[e] = ok ? x : NEG_INF;
  }
  float wm = wred_max(fmaxf(fmaxf(v[0], v[1]), fmaxf(v[2], v[3])));
  if ((tid & 63) == 0) sm[wid] = wm;
  __syncthreads();
  const float mx = fmaxf(sm[half * 2], sm[half * 2 + 1]);
  float e0 = expf(v[0] - mx), e1 = expf(v[1] - mx);
  float e2 = expf(v[2] - mx), e3 = expf(v[3] - mx);
  float ws = wred_sum(e0 + e1 + e2 + e3);
  __syncthreads();                        // protect sm before overwrite
  if ((tid & 63) == 0) sm[wid] = ws;
  __syncthreads();
  const float inv = 1.f / (sm[half * 2] + sm[half * 2 + 1]);
  const u16x4 o = {f2bf(e0 * inv), f2bf(e1 * inv), f2bf(e2 * inv), f2bf(e3 * inv)};
  *(u16x4*)(prow + j0) = o;
}

// log_softmax over V=32000: f16 logits live in the first half of each f32
// output row of d_out. Stage row in LDS, reduce, write f32 logprobs.
__global__ __launch_bounds__(512)
void log_softmax_kernel(float* __restrict__ out) {
  __shared__ u16 row[32000];
  __shared__ float sm[8];
  const int m = blockIdx.x, tid = threadIdx.x;
  const u16* src = (const u16*)out + (size_t)m * 64000u;
  for (int c = tid; c < 4000; c += 512)
    *(u16x8*)&row[c * 8] = *(const u16x8*)(src + c * 8);
  __syncthreads();
  float mx = NEG_INF;
  for (int c = tid; c < 4000; c += 512) {
    const u16x8 h = *(const u16x8*)&row[c * 8];
#pragma unroll
    for (int e = 0; e < 8; ++e) mx = fmaxf(mx, f16tof(h[e]));
  }
  mx = wred_max(mx);
  if ((tid & 63) == 0) sm[tid >> 6] = mx;
  __syncthreads();
  if (tid == 0) {
    float a = sm[0];
#pragma unroll
    for (int wI = 1; wI < 8; ++wI) a = fmaxf(a, sm[wI]);
    sm[0] = a;
  }
  __syncthreads();
  mx = sm[0];
  __syncthreads();
  float s = 0.f;
  for (int c = tid; c < 4000; c += 512) {
    const u16x8 h = *(const u16x8*)&row[c * 8];
#pragma unroll
    for (int e = 0; e < 8; ++e) s += expf(f16tof(h[e]) - mx);
  }
  s = wred_sum(s);
  if ((tid & 63) == 0) sm[tid >> 6] = s;
  __syncthreads();
  if (tid == 0) {
    float a = 0.f;
#pragma unroll
    for (int wI = 0; wI < 8; ++wI) a += sm[wI];
    sm[0] = a;
  }
  __syncthreads();
  const float lse = mx + logf(sm[0]);
  float* dst = out + (size_t)m * 32000u;
  for (int c = tid; c < 4000; c += 512) {
    const u16x8 h = *(const u16x8*)&row[c * 8];
    float4 o0, o1;
    o0.x = f16tof(h[0]) - lse; o0.y = f16tof(h[1]) - lse;
    o0.z = f16tof(h[2]) - lse; o0.w = f16tof(h[3]) - lse;
    o1.x = f16tof(h[4]) - lse; o1.y = f16tof(h[5]) - lse;
    o1.z = f16tof(h[6]) - lse; o1.w = f16tof(h[7]) - lse;
    ((float4*)dst)[c * 2]     = o0;
    ((float4*)dst)[c * 2 + 1] = o1;
  }
}

// ---------------------------------------------------------------------------
// host driver
// ---------------------------------------------------------------------------
extern "C" void kernel_launch(void* const* d_in, const int* in_sizes, int n_in,
                              void* d_out, int out_size, void* d_ws, size_t ws_size,
                              hipStream_t stream) {
  const float* enc_out = (const float*)d_in[0];
  const int*   dec_in  = (const int*)d_in[1];
  const int*   enc_in  = (const int*)d_in[2];
  const float* emb     = (const float*)d_in[3];
  const float* wq1 = (const float*)d_in[4];  const float* bq1 = (const float*)d_in[5];
  const float* wk1 = (const float*)d_in[6];  const float* bk1 = (const float*)d_in[7];
  const float* wv1 = (const float*)d_in[8];  const float* bv1 = (const float*)d_in[9];
  const float* wo1 = (const float*)d_in[10]; const float* bo1 = (const float*)d_in[11];
  const float* pos1 = (const float*)d_in[12];
  const float* wq2 = (const float*)d_in[13]; const float* bq2 = (const float*)d_in[14];
  const float* wk2 = (const float*)d_in[15]; const float* bk2 = (const float*)d_in[16];
  const float* wv2 = (const float*)d_in[17]; const float* bv2 = (const float*)d_in[18];
  const float* wo2 = (const float*)d_in[19]; const float* bo2 = (const float*)d_in[20];
  const float* ln1g = (const float*)d_in[21]; const float* ln1b = (const float*)d_in[22];
  const float* ln2g = (const float*)d_in[23]; const float* ln2b = (const float*)d_in[24];
  const float* ln3g = (const float*)d_in[25]; const float* ln3b = (const float*)d_in[26];
  const float* wf1 = (const float*)d_in[27]; const float* bf1 = (const float*)d_in[28];
  const float* wf2 = (const float*)d_in[29]; const float* bf2 = (const float*)d_in[30];
  const float* wout = (const float*)d_in[31]; const float* bout = (const float*)d_in[32];

  char* ws = (char*)d_ws;
  u16*   WT    = (u16*)(ws + 0);             // 32MB  (per-layer transposed weights)
  u16*   SCb   = (u16*)(ws + 33554432);      // 32MB  scores bf16 [64][512][512]
  u16*   WoutT = (u16*)(ws + 0);             // 65.5MB, overlaps WT+SCb (used at end)
  u16*   PEP   = (u16*)(ws + 67108864);      // 32MB  PE / P bf16 [32768][512]
  float* X     = (float*)(ws + 100663296);   // 8MB
  float* Xa    = (float*)(ws + 109051904);   // 8MB
  float* Xb    = (float*)(ws + 117440512);   // 8MB
  float* Rb    = (float*)(ws + 125829120);   // 8MB
  u16*   Ab16  = (u16*)(ws + 134217728);     // 4MB  current GEMM-input activation
  u16*   Q     = (u16*)(ws + 138412032);     // 4MB  [g][512][64]
  u16*   Kh    = (u16*)(ws + 142606336);     // 4MB  [g][512][64]
  u16*   VT    = (u16*)(ws + 146800640);     // 8MB  [g][128(pad)][512]
  u16*   Ob16  = (u16*)(ws + 155189248);     // 4MB  merged attn out
  u16*   FFH16 = (u16*)(ws + 159383552);     // 16MB [2048][4096]
  u16*   encb  = (u16*)(ws + 176160768);     // 4MB  encoder_outputs bf16
  u16*   posb  = (u16*)(ws + 180355072);     // 384KB [6][512][64]
  float* out   = (float*)d_out;

  embed_kernel<<<2048, 256, 0, stream>>>(dec_in, emb, X, Ab16);
  conv_bf16<<<2048, 256, 0, stream>>>(enc_out, encb);
  conv_pos<<<192, 256, 0, stream>>>(pos1, posb);

  for (int i = 0; i < 6; ++i) {
    const size_t oHH = (size_t)i * 1048576u, oH = (size_t)i * 1024u;
    const float* bq1i = bq1 + oH; const float* bk1i = bk1 + oH;
    const float* bv1i = bv1 + oH; const float* bo1i = bo1 + oH;
    const float* bq2i = bq2 + oH; const float* bk2i = bk2 + oH;
    const float* bv2i = bv2 + oH; const float* bo2i = bo2 + oH;
    const float* bf1i = bf1 + (size_t)i * 4096u; const float* bf2i = bf2 + oH;
    const u16* posL = posb + (size_t)i * 32768u;

    conv_layer<<<4096, 256, 0, stream>>>(
        wq1 + oHH, wk1 + oHH, wv1 + oHH, wo1 + oHH,
        wq2 + oHH, wk2 + oHH, wv2 + oHH, wo2 + oHH,
        wf1 + (size_t)i * 4194304u, wf2 + (size_t)i * 4194304u, WT);

    // ---- self attention ----
    bgemm<4, true, 4, false, false, false><<<dim3(24, 16, 1), 256, 0, stream>>>(
        Ab16, 0, WT, 0, bq1i, bk1i, bv1i, nullptr, Q, Kh, VT, 0, 0, 1024, 0.125f);
    bgemm<0, true, 4, false, false, false><<<dim3(4, 256, 1), 256, 0, stream>>>(
        Q, 0, posL, 0, nullptr, nullptr, nullptr, nullptr, PEP, nullptr, nullptr,
        0, 512, 64, 1.f);
    bgemm<0, true, 4, false, false, true><<<dim3(4, 4, 64), 256, 0, stream>>>(
        Q, 32768, Kh, 32768, nullptr, nullptr, nullptr, nullptr, SCb, nullptr, nullptr,
        262144, 512, 64, 1.f);
    softmax_rows<true><<<dim3(256, 64), 256, 0, stream>>>(SCb, PEP, dec_in);
    bgemm<3, true, 4, false, false, false><<<dim3(1, 4, 64), 256, 0, stream>>>(
        PEP, 262144, VT, 65536, nullptr, nullptr, nullptr, nullptr, Ob16, nullptr, nullptr,
        0, 0, 512, 1.f);
    bgemm<0, false, 2, false, true, false><<<dim3(8, 32, 1), 256, 0, stream>>>(
        Ob16, 0, WT + 3145728u, 0, bo1i, nullptr, nullptr, X, Rb, nullptr, nullptr,
        0, 1024, 1024, 1.f);
    layernorm_kernel<<<2048, 256, 0, stream>>>(Rb, ln1g + oH, ln1b + oH, Xa, Ab16);

    // ---- cross attention ----
    bgemm<1, true, 2, false, false, false><<<dim3(8, 32, 1), 256, 0, stream>>>(
        Ab16, 0, WT + 4194304u, 0, bq2i, nullptr, nullptr, nullptr, Q, nullptr, nullptr,
        0, 0, 1024, 0.125f);
    bgemm<5, true, 4, false, false, false><<<dim3(16, 16, 1), 256, 0, stream>>>(
        encb, 0, WT + 5242880u, 0, bk2i, bv2i, nullptr, nullptr, Kh, VT, nullptr,
        0, 0, 1024, 1.f);
    bgemm<0, true, 4, false, false, false><<<dim3(4, 4, 64), 256, 0, stream>>>(
        Q, 32768, Kh, 32768, nullptr, nullptr, nullptr, nullptr, SCb, nullptr, nullptr,
        262144, 512, 64, 1.f);
    softmax_rows<false><<<dim3(256, 64), 256, 0, stream>>>(SCb, PEP, enc_in);
    bgemm<3, true, 4, false, false, false><<<dim3(1, 4, 64), 256, 0, stream>>>(
        PEP, 262144, VT, 65536, nullptr, nullptr, nullptr, nullptr, Ob16, nullptr, nullptr,
        0, 0, 512, 1.f);
    bgemm<0, false, 2, false, true, false><<<dim3(8, 32, 1), 256, 0, stream>>>(
        Ob16, 0, WT + 7340032u, 0, bo2i, nullptr, nullptr, Xa, Rb, nullptr, nullptr,
        0, 1024, 1024, 1.f);
    layernorm_kernel<<<2048, 256, 0, stream>>>(Rb, ln2g + oH, ln2b + oH, Xb, Ab16);

    // ---- FFN ----
    bgemm<0, true, 4, true, false, false><<<dim3(32, 16, 1), 256, 0, stream>>>(
        Ab16, 0, WT + 8388608u, 0, bf1i, nullptr, nullptr, nullptr, FFH16, nullptr, nullptr,
        0, 4096, 1024, 1.f);
    bgemm<0, false, 2, false, true, false><<<dim3(8, 32, 1), 256, 0, stream>>>(
        FFH16, 0, WT + 12582912u, 0, bf2i, nullptr, nullptr, Xb, Rb, nullptr, nullptr,
        0, 1024, 4096, 1.f);
    layernorm_kernel<<<2048, 256, 0, stream>>>(Rb, ln3g + oH, ln3b + oH, X, Ab16);
  }

  // ---- output head (f16 logits into d_out row-halves) + log_softmax ----
  conv_wout<<<8000, 256, 0, stream>>>(wout, WoutT);
  bgemm<6, false, 4, false, false, false><<<dim3(250, 16, 1), 256, 0, stream>>>(
      Ab16, 0, WoutT, 0, bout, nullptr, nullptr, nullptr, out, nullptr, nullptr,
      0, 64000, 1024, 1.f);
  log_softmax_kernel<<<2048, 512, 0, stream>>>(out);
}

// Round 4
// 2311.039 us; speedup vs baseline: 3.0601x; 1.0166x over previous
//
#include <hip/hip_runtime.h>

// ---------------------------------------------------------------------------
// TransformerDecoder forward on MI355X (gfx950) — round 4.
// Round-4 deltas: fused attention kernels (QK^T + skew + mask + softmax + PV
// in one dispatch, scores never touch HBM), PE band-skip GEMM, head GEMM
// GM=16 rasterization, precomputed -inf/0 pad masks.
// ---------------------------------------------------------------------------

typedef unsigned short u16;
typedef short s16x8 __attribute__((ext_vector_type(8)));
typedef unsigned short u16x4 __attribute__((ext_vector_type(4)));
typedef unsigned short u16x8 __attribute__((ext_vector_type(8)));
typedef float f32x4 __attribute__((ext_vector_type(4)));

#define PADTOK 2
#define NEG_INF (-__builtin_inff())

static __device__ __forceinline__ u16 f2bf(float f) {
  unsigned u = __float_as_uint(f);
  u += 0x7fffu + ((u >> 16) & 1u);
  return (u16)(u >> 16);
}
static __device__ __forceinline__ float bf2f(u16 h) {
  return __uint_as_float(((unsigned)h) << 16);
}
static __device__ __forceinline__ float f16tof(u16 h) {
  _Float16 x = __builtin_bit_cast(_Float16, h);
  return (float)x;
}
static __device__ __forceinline__ u16 ftof16(float v) {
  _Float16 x = (_Float16)v;
  return __builtin_bit_cast(u16, x);
}
static __device__ __forceinline__ f32x4 mfma16(s16x8 a, s16x8 b, f32x4 c) {
  asm("v_mfma_f32_16x16x32_bf16 %0, %1, %2, %0" : "+v"(c) : "v"(a), "v"(b));
  return c;
}
static __device__ __forceinline__ void gll16(const void* g, void* l) {
  __builtin_amdgcn_global_load_lds((const __attribute__((address_space(1))) void*)g,
                                   (__attribute__((address_space(3))) void*)l, 16, 0, 0);
}
static __device__ __forceinline__ size_t hsidx(int m, int n) {
  return ((size_t)((m >> 9) * 16 + (n >> 6))) * 32768u + (size_t)(m & 511) * 64u + (size_t)(n & 63);
}
static __device__ __forceinline__ size_t vtidx(int m, int n) {
  return ((size_t)((m >> 9) * 16 + (n >> 6))) * 65536u + (size_t)(n & 63) * 512u + (size_t)(m & 511);
}

// XCD-chunked (bijective) + m-grouped n-major rasterization.
static __device__ __forceinline__ void raster2(int& bm, int& bn, int GM0) {
  const int nm = gridDim.y, nn = gridDim.x;
  int bid = blockIdx.y * nn + blockIdx.x;
  const int nwg = nm * nn;
  const int q = nwg >> 3, r = nwg & 7;
  const int x = bid & 7, p = bid >> 3;
  bid = (x < r ? x * (q + 1) : r * (q + 1) + (x - r) * q) + p;
  const int GM = nm < GM0 ? nm : GM0;
  const int pg = GM * nn;
  const int gi = bid / pg, rem = bid - gi * pg;
  const int left = nm - gi * GM;
  const int gm = left < GM ? left : GM;
  bm = gi * GM + rem % gm;
  bn = rem / gm;
}

// ---------------------------------------------------------------------------
// bf16 GEMM: C = epi(A[M,K] @ Bt[N,K]^T) per batch g. BM=MFR*32, BN=128, BK=64.
// EPI: 0 plain  1 headsplit  4 QKV-fused  5 KV-fused  6 f16 out
// SKIP: 0 none  1 causal (unused now)  2 PE band-skip
// ---------------------------------------------------------------------------
template<int EPI, bool BF16OUT, int MFR, bool RELU, bool RESID, int SKIP, int GMT>
__global__ __launch_bounds__(256)
void bgemm(const u16* __restrict__ A, long long sAg,
           const u16* __restrict__ Bt, long long sBg,
           const float* __restrict__ bias, const float* __restrict__ bias2,
           const float* __restrict__ bias3,
           const float* __restrict__ Res,
           void* __restrict__ Cv, u16* __restrict__ C2, u16* __restrict__ C3,
           long long sCg, int ldc, int K, float scale)
{
  constexpr int BM = MFR * 32;
  __shared__ u16 As[BM * 64];
  __shared__ u16 Bs[128 * 64];
  int bmi, bni;
  raster2(bmi, bni, GMT);
  const int bm0 = bmi * BM, bn0 = bni * 128;
  if constexpr (SKIP == 1) {
    if (bn0 > bm0 + BM - 1) return;
  }
  if constexpr (SKIP == 2) {          // PE: tile unread iff (i0&511)+n0 <= 256
    if ((bm0 & 511) + bn0 <= 256) return;
  }
  const int g = blockIdx.z;
  const u16* Ag = A + (size_t)g * (size_t)sAg;
  const u16* Bg = Bt + (size_t)g * (size_t)sBg;
  const int tid = threadIdx.x, l = tid & 63, w = tid >> 6;
  const int wm = w >> 1, wn = w & 1;
  const int rsel = l & 15, kg = l >> 4, xs = l & 7;

  f32x4 acc[MFR][4];
#pragma unroll
  for (int i = 0; i < MFR; ++i)
#pragma unroll
    for (int j = 0; j < 4; ++j) acc[i][j] = (f32x4){0.f, 0.f, 0.f, 0.f};

  const int srow = l >> 3;               // row within 8-row group
  const int sch  = (l & 7) ^ srow;       // swizzled source chunk
  const u16* Agp = Ag + ((size_t)(bm0 + w * 8 * MFR + srow)) * (size_t)K + sch * 8;
  const u16* Bgp = Bg + ((size_t)(bn0 + w * 32 + srow)) * (size_t)K + sch * 8;
  char* AsL = (char*)As + (w * 8 * MFR) * 128;
  char* BsL = (char*)Bs + (w * 32) * 128;

  for (int k0 = 0; k0 < K; k0 += 64) {
    __syncthreads();
#pragma unroll
    for (int i = 0; i < MFR; ++i)
      gll16(Agp + (size_t)i * 8 * K + k0, AsL + i * 1024);
#pragma unroll
    for (int i = 0; i < 4; ++i)
      gll16(Bgp + (size_t)i * 8 * K + k0, BsL + i * 1024);
    __syncthreads();

    const int arow0 = (wm * (MFR * 16) + rsel) * 128;
    const int brow0 = (wn * 64 + rsel) * 128;
#pragma unroll
    for (int ks = 0; ks < 2; ++ks) {
      const int ch = ((ks * 4 + kg) ^ xs) * 16;
      s16x8 af[MFR], bfr[4];
#pragma unroll
      for (int mf = 0; mf < MFR; ++mf)
        af[mf] = *(const s16x8*)((const char*)As + arow0 + mf * 2048 + ch);
#pragma unroll
      for (int nf = 0; nf < 4; ++nf)
        bfr[nf] = *(const s16x8*)((const char*)Bs + brow0 + nf * 2048 + ch);
#pragma unroll
      for (int mf = 0; mf < MFR; ++mf)
#pragma unroll
        for (int nf = 0; nf < 4; ++nf)
          acc[mf][nf] = mfma16(af[mf], bfr[nf], acc[mf][nf]);
    }
  }

  // epilogue: C/D layout col=lane&15 (n), row=(lane>>4)*4+e (m)
#pragma unroll
  for (int mf = 0; mf < MFR; ++mf) {
#pragma unroll
    for (int nf = 0; nf < 4; ++nf) {
      const int n = bn0 + wn * 64 + nf * 16 + rsel;
      int sub = 0, nl = n;
      const float* bp = bias;
      if constexpr (EPI == 4) {
        sub = n >> 10; nl = n & 1023;
        bp = (sub == 0) ? bias : (sub == 1) ? bias2 : bias3;
      }
      if constexpr (EPI == 5) {
        sub = n >> 10; nl = n & 1023;
        bp = (sub == 0) ? bias : bias2;
      }
      const float bv = bp ? bp[nl] : 0.f;
      float sc = 1.f;
      if constexpr (EPI == 0 || EPI == 1) sc = scale;
      if constexpr (EPI == 4) sc = (sub == 0) ? scale : 1.f;
#pragma unroll
      for (int e = 0; e < 4; ++e) {
        const int m = bm0 + wm * (MFR * 16) + mf * 16 + kg * 4 + e;
        float v = (acc[mf][nf][e] + bv) * sc;
        if constexpr (RELU) v = fmaxf(v, 0.f);
        if constexpr (RESID) v += Res[(size_t)m * (size_t)ldc + n];
        if constexpr (EPI == 0) {
          const size_t idx = (size_t)g * (size_t)sCg + (size_t)m * (size_t)ldc + n;
          if constexpr (BF16OUT) ((u16*)Cv)[idx] = f2bf(v);
          else                   ((float*)Cv)[idx] = v;
        } else if constexpr (EPI == 1) {
          ((u16*)Cv)[hsidx(m, nl)] = f2bf(v);
        } else if constexpr (EPI == 4) {
          if (sub == 2)      C3[vtidx(m, nl)] = f2bf(v);
          else if (sub == 1) C2[hsidx(m, nl)] = f2bf(v);
          else               ((u16*)Cv)[hsidx(m, nl)] = f2bf(v);
        } else if constexpr (EPI == 5) {
          if (sub == 0) ((u16*)Cv)[hsidx(m, nl)] = f2bf(v);
          else          C2[vtidx(m, nl)] = f2bf(v);
        } else if constexpr (EPI == 6) {
          ((u16*)Cv)[(size_t)m * (size_t)ldc + n] = ftof16(v);
        }
      }
    }
  }
}

// ---------------------------------------------------------------------------
// fused attention: one block = (b,h) x 32 Q-rows. QK^T (+skew+masks) ->
// softmax -> PV, scores stay in LDS. Q/K: [g][512][64] bf16. V: [g][128][512]
// (V^T rows, 0..63 used). O: merged [b][512][1024] bf16.
// ---------------------------------------------------------------------------
template<bool SELF>
__global__ __launch_bounds__(256)
void fused_attn(const u16* __restrict__ Qb, const u16* __restrict__ Kb,
                const u16* __restrict__ Vt, const u16* __restrict__ PE,
                const float* __restrict__ maskf, u16* __restrict__ O)
{
  __shared__ u16 SP[32][520];          // scores -> P (bf16), 16B-aligned rows
  __shared__ float Of[4][32][68];      // per-wave PV partials
  __shared__ float rs[32];             // 1/rowsum
  const int it = blockIdx.x, g = blockIdx.y, b = g >> 4, h = g & 15;
  const int i0 = it * 32;
  const int CT = SELF ? (i0 + 32) : 512;
  const int tid = threadIdx.x, l = tid & 63, w = tid >> 6;
  const int rsel = l & 15, kg = l >> 4;

  const u16* Qg = Qb + (size_t)g * 32768u;
  const u16* Kg = Kb + (size_t)g * 32768u;
  const u16* Vg = Vt + (size_t)g * 65536u;

  // Q fragments for 32 rows x 64 d (2 row-tiles x 2 k-steps)
  s16x8 qf[2][2];
#pragma unroll
  for (int rt = 0; rt < 2; ++rt)
#pragma unroll
    for (int ks = 0; ks < 2; ++ks)
      qf[rt][ks] = *(const s16x8*)(Qg + (size_t)(i0 + rt * 16 + rsel) * 64u + ks * 32 + kg * 8);

  // ---- QK^T: wave w owns col-tiles ct = w, w+4, ... ----
  for (int ct = w; ct * 16 < CT; ct += 4) {
    const int j = ct * 16 + rsel;
    const s16x8 kf0 = *(const s16x8*)(Kg + (size_t)j * 64u + kg * 8);
    const s16x8 kf1 = *(const s16x8*)(Kg + (size_t)j * 64u + 32 + kg * 8);
    f32x4 a0 = {0.f, 0.f, 0.f, 0.f}, a1 = {0.f, 0.f, 0.f, 0.f};
    a0 = mfma16(qf[0][0], kf0, a0);
    a0 = mfma16(qf[0][1], kf1, a0);
    a1 = mfma16(qf[1][0], kf0, a1);
    a1 = mfma16(qf[1][1], kf1, a1);
    const float mj = maskf[b * 512 + j];
#pragma unroll
    for (int rt = 0; rt < 2; ++rt) {
      const f32x4 av = rt ? a1 : a0;
#pragma unroll
      for (int e = 0; e < 4; ++e) {
        const int r = rt * 16 + kg * 4 + e;
        float v = av[e] + mj;
        if constexpr (SELF) {
          const int i = i0 + r;
          if (j > i) v = NEG_INF;
          else       v += bf2f(PE[((size_t)(g * 512 + i)) * 512u + (511 + j - i)]);
        }
        SP[r][j] = f2bf(v);
      }
    }
  }
  __syncthreads();

  // ---- softmax: row r = tid>>3, 8 threads/row, 4 cols/thread, stride 32 ----
  const int r = tid >> 3, sc0 = (tid & 7) * 4;
  float mx = NEG_INF;
  for (int c = sc0; c < CT; c += 32) {
    const u16x4 h4 = *(const u16x4*)&SP[r][c];
#pragma unroll
    for (int e = 0; e < 4; ++e) mx = fmaxf(mx, bf2f(h4[e]));
  }
#pragma unroll
  for (int o = 1; o < 8; o <<= 1) mx = fmaxf(mx, __shfl_xor(mx, o, 64));
  float sum = 0.f;
  for (int c = sc0; c < CT; c += 32) {
    const u16x4 h4 = *(const u16x4*)&SP[r][c];
    const float p0 = expf(bf2f(h4[0]) - mx), p1 = expf(bf2f(h4[1]) - mx);
    const float p2 = expf(bf2f(h4[2]) - mx), p3 = expf(bf2f(h4[3]) - mx);
    sum += p0 + p1 + p2 + p3;
    const u16x4 o4 = {f2bf(p0), f2bf(p1), f2bf(p2), f2bf(p3)};
    *(u16x4*)&SP[r][c] = o4;           // unnormalized P; scale at O-write
  }
#pragma unroll
  for (int o = 1; o < 8; o <<= 1) sum += __shfl_xor(sum, o, 64);
  if ((tid & 7) == 0) rs[r] = 1.f / sum;
  __syncthreads();

  // ---- PV: wave w owns k-tiles kt = w, w+4, ... ----
  f32x4 oa[2][4];
#pragma unroll
  for (int rt = 0; rt < 2; ++rt)
#pragma unroll
    for (int nt = 0; nt < 4; ++nt) oa[rt][nt] = (f32x4){0.f, 0.f, 0.f, 0.f};
  const int nk = CT >> 5;
  for (int kt = w; kt < nk; kt += 4) {
    const s16x8 pf0 = *(const s16x8*)&SP[rsel][kt * 32 + kg * 8];
    const s16x8 pf1 = *(const s16x8*)&SP[16 + rsel][kt * 32 + kg * 8];
    s16x8 vf[4];
#pragma unroll
    for (int nt = 0; nt < 4; ++nt)
      vf[nt] = *(const s16x8*)(Vg + (size_t)(nt * 16 + rsel) * 512u + kt * 32 + kg * 8);
#pragma unroll
    for (int nt = 0; nt < 4; ++nt) {
      oa[0][nt] = mfma16(pf0, vf[nt], oa[0][nt]);
      oa[1][nt] = mfma16(pf1, vf[nt], oa[1][nt]);
    }
  }
#pragma unroll
  for (int rt = 0; rt < 2; ++rt)
#pragma unroll
    for (int nt = 0; nt < 4; ++nt)
#pragma unroll
      for (int e = 0; e < 4; ++e)
        Of[w][rt * 16 + kg * 4 + e][nt * 16 + rsel] = oa[rt][nt][e];
  __syncthreads();

  // ---- cross-wave reduce + scale + merged-head write ----
  const int c0 = (tid & 7) * 8;
  const float inv = rs[r];
  float ov[8];
#pragma unroll
  for (int q = 0; q < 2; ++q) {
    const float4 s0 = *(const float4*)&Of[0][r][c0 + q * 4];
    const float4 s1 = *(const float4*)&Of[1][r][c0 + q * 4];
    const float4 s2 = *(const float4*)&Of[2][r][c0 + q * 4];
    const float4 s3 = *(const float4*)&Of[3][r][c0 + q * 4];
    ov[q * 4 + 0] = (s0.x + s1.x + s2.x + s3.x) * inv;
    ov[q * 4 + 1] = (s0.y + s1.y + s2.y + s3.y) * inv;
    ov[q * 4 + 2] = (s0.z + s1.z + s2.z + s3.z) * inv;
    ov[q * 4 + 3] = (s0.w + s1.w + s2.w + s3.w) * inv;
  }
  const u16x8 o8 = {f2bf(ov[0]), f2bf(ov[1]), f2bf(ov[2]), f2bf(ov[3]),
                    f2bf(ov[4]), f2bf(ov[5]), f2bf(ov[6]), f2bf(ov[7])};
  *(u16x8*)(O + ((size_t)(b * 512 + i0 + r)) * 1024u + h * 64 + c0) = o8;
}

// ---------------------------------------------------------------------------
// transpose+convert f32[K,N] -> bf16[N,K], 64x64 tiles
// ---------------------------------------------------------------------------
static __device__ __forceinline__ void tconv_tile(const float* in, int N,
                                                  u16* out, int K, int k0, int n0) {
  __shared__ u16 L[64][72];
  const int t = threadIdx.x;
  const int rk = t >> 4, cn = (t & 15) * 4;
#pragma unroll
  for (int q = 0; q < 4; ++q) {
    const int kk = k0 + rk + q * 16;
    float4 v = *(const float4*)(in + (size_t)kk * (size_t)N + n0 + cn);
    L[cn + 0][rk + q * 16] = f2bf(v.x);
    L[cn + 1][rk + q * 16] = f2bf(v.y);
    L[cn + 2][rk + q * 16] = f2bf(v.z);
    L[cn + 3][rk + q * 16] = f2bf(v.w);
  }
  __syncthreads();
  const int rn = t >> 2, ck = (t & 3) * 16;
  u16* op = out + (size_t)(n0 + rn) * (size_t)K + k0 + ck;
  *(s16x8*)op       = *(const s16x8*)&L[rn][ck];
  *(s16x8*)(op + 8) = *(const s16x8*)&L[rn][ck + 8];
}

__global__ __launch_bounds__(256)
void conv_layer(const float* w0, const float* w1, const float* w2, const float* w3,
                const float* w4, const float* w5, const float* w6, const float* w7,
                const float* w8, const float* w9, u16* WT) {
  const int b = blockIdx.x;
  const float* in; u16* out; int N, K, kt, nt;
  if (b < 2048) {
    const int j = b >> 8, t = b & 255;
    const float* ws[8] = {w0, w1, w2, w3, w4, w5, w6, w7};
    in = ws[j]; out = WT + (size_t)j * 1048576u; K = 1024; N = 1024;
    kt = t >> 4; nt = t & 15;
  } else if (b < 3072) {
    const int t = b - 2048;
    in = w8; out = WT + 8388608u; K = 1024; N = 4096; kt = t >> 6; nt = t & 63;
  } else {
    const int t = b - 3072;
    in = w9; out = WT + 12582912u; K = 4096; N = 1024; kt = t >> 4; nt = t & 15;
  }
  tconv_tile(in, N, out, K, kt * 64, nt * 64);
}

__global__ __launch_bounds__(256)
void conv_wout(const float* in, u16* out) {
  const int b = blockIdx.x;            // 8000 = 16 ktiles * 500 ntiles
  const int kt = b / 500, nt = b % 500;
  tconv_tile(in, 32000, out, 1024, kt * 64, nt * 64);
}

// ---------------------------------------------------------------------------
// elementwise converts / masks
// ---------------------------------------------------------------------------
__global__ void conv_bf16(const float* __restrict__ in, u16* __restrict__ out) {
  const int i = (blockIdx.x * 256 + threadIdx.x) * 4;
  float4 v = *(const float4*)(in + i);
  u16x4 h = {f2bf(v.x), f2bf(v.y), f2bf(v.z), f2bf(v.w)};
  *(u16x4*)(out + i) = h;
}

__global__ void conv_pos(const float* __restrict__ pos, u16* __restrict__ posb) {
  const int idx = (blockIdx.x * 256 + threadIdx.x) * 4;   // over 6*512*64
  const int lyr = idx >> 15, rem = idx & 32767;
  float4 v = *(const float4*)(pos + (size_t)lyr * 65472u + rem);
  u16x4 h = {f2bf(v.x), f2bf(v.y), f2bf(v.z), f2bf(v.w)};
  *(u16x4*)(posb + idx) = h;
}

__global__ void mask_kernel(const int* __restrict__ dec, const int* __restrict__ enc,
                            float* __restrict__ mD, float* __restrict__ mE) {
  const int i = blockIdx.x * 256 + threadIdx.x;   // 2048
  mD[i] = (dec[i] == PADTOK) ? NEG_INF : 0.f;
  mE[i] = (enc[i] == PADTOK) ? NEG_INF : 0.f;
}

// ---------------------------------------------------------------------------
// reductions
// ---------------------------------------------------------------------------
static __device__ __forceinline__ float wred_sum(float v) {
#pragma unroll
  for (int o = 32; o > 0; o >>= 1) v += __shfl_down(v, o, 64);
  return v;
}
static __device__ __forceinline__ float wred_max(float v) {
#pragma unroll
  for (int o = 32; o > 0; o >>= 1) v = fmaxf(v, __shfl_down(v, o, 64));
  return v;
}
static __device__ __forceinline__ float bred_sum(float v, float* sm) {
  const int lane = threadIdx.x & 63, wid = threadIdx.x >> 6;
  v = wred_sum(v);
  if (lane == 0) sm[wid] = v;
  __syncthreads();
  if (threadIdx.x == 0) sm[0] = sm[0] + sm[1] + sm[2] + sm[3];
  __syncthreads();
  const float r = sm[0];
  __syncthreads();
  return r;
}

// ---------------------------------------------------------------------------
// small kernels
// ---------------------------------------------------------------------------
__global__ void embed_kernel(const int* __restrict__ dec, const float* __restrict__ emb,
                             float* __restrict__ X, u16* __restrict__ Xh) {
  const int m = blockIdx.x, t = threadIdx.x;
  const int tok = dec[m];
  float4 v = ((const float4*)(emb + (size_t)tok * 1024u))[t];
  ((float4*)(X + (size_t)m * 1024u))[t] = v;
  u16x4 h = {f2bf(v.x), f2bf(v.y), f2bf(v.z), f2bf(v.w)};
  *(u16x4*)(Xh + (size_t)m * 1024u + t * 4) = h;
}

__global__ void layernorm_kernel(const float* __restrict__ R,
                                 const float* __restrict__ gw, const float* __restrict__ bw,
                                 float* __restrict__ Y, u16* __restrict__ Yh) {
  __shared__ float sm[4];
  const int m = blockIdx.x, t = threadIdx.x;
  float4 v = ((const float4*)(R + (size_t)m * 1024u))[t];
  float s = v.x + v.y + v.z + v.w;
  s = bred_sum(s, sm);
  const float mean = s * (1.f / 1024.f);
  const float d0 = v.x - mean, d1 = v.y - mean, d2 = v.z - mean, d3 = v.w - mean;
  float q = d0 * d0 + d1 * d1 + d2 * d2 + d3 * d3;
  q = bred_sum(q, sm);
  const float rstd = rsqrtf(q * (1.f / 1024.f) + 1e-5f);
  const int c = t * 4;
  float4 o;
  o.x = d0 * rstd * gw[c + 0] + bw[c + 0];
  o.y = d1 * rstd * gw[c + 1] + bw[c + 1];
  o.z = d2 * rstd * gw[c + 2] + bw[c + 2];
  o.w = d3 * rstd * gw[c + 3] + bw[c + 3];
  ((float4*)(Y + (size_t)m * 1024u))[t] = o;
  u16x4 h = {f2bf(o.x), f2bf(o.y), f2bf(o.z), f2bf(o.w)};
  *(u16x4*)(Yh + (size_t)m * 1024u + c) = h;
}

// log_softmax over V=32000: f16 logits live in the first half of each f32
// output row of d_out. Stage row in LDS, reduce, write f32 logprobs.
__global__ __launch_bounds__(512)
void log_softmax_kernel(float* __restrict__ out) {
  __shared__ u16 row[32000];
  __shared__ float sm[8];
  const int m = blockIdx.x, tid = threadIdx.x;
  const u16* src = (const u16*)out + (size_t)m * 64000u;
  for (int c = tid; c < 4000; c += 512)
    *(u16x8*)&row[c * 8] = *(const u16x8*)(src + c * 8);
  __syncthreads();
  float mx = NEG_INF;
  for (int c = tid; c < 4000; c += 512) {
    const u16x8 h = *(const u16x8*)&row[c * 8];
#pragma unroll
    for (int e = 0; e < 8; ++e) mx = fmaxf(mx, f16tof(h[e]));
  }
  mx = wred_max(mx);
  if ((tid & 63) == 0) sm[tid >> 6] = mx;
  __syncthreads();
  if (tid == 0) {
    float a = sm[0];
#pragma unroll
    for (int wI = 1; wI < 8; ++wI) a = fmaxf(a, sm[wI]);
    sm[0] = a;
  }
  __syncthreads();
  mx = sm[0];
  __syncthreads();
  float s = 0.f;
  for (int c = tid; c < 4000; c += 512) {
    const u16x8 h = *(const u16x8*)&row[c * 8];
#pragma unroll
    for (int e = 0; e < 8; ++e) s += expf(f16tof(h[e]) - mx);
  }
  s = wred_sum(s);
  if ((tid & 63) == 0) sm[tid >> 6] = s;
  __syncthreads();
  if (tid == 0) {
    float a = 0.f;
#pragma unroll
    for (int wI = 0; wI < 8; ++wI) a += sm[wI];
    sm[0] = a;
  }
  __syncthreads();
  const float lse = mx + logf(sm[0]);
  float* dst = out + (size_t)m * 32000u;
  for (int c = tid; c < 4000; c += 512) {
    const u16x8 h = *(const u16x8*)&row[c * 8];
    float4 o0, o1;
    o0.x = f16tof(h[0]) - lse; o0.y = f16tof(h[1]) - lse;
    o0.z = f16tof(h[2]) - lse; o0.w = f16tof(h[3]) - lse;
    o1.x = f16tof(h[4]) - lse; o1.y = f16tof(h[5]) - lse;
    o1.z = f16tof(h[6]) - lse; o1.w = f16tof(h[7]) - lse;
    ((float4*)dst)[c * 2]     = o0;
    ((float4*)dst)[c * 2 + 1] = o1;
  }
}

// ---------------------------------------------------------------------------
// host driver
// ---------------------------------------------------------------------------
extern "C" void kernel_launch(void* const* d_in, const int* in_sizes, int n_in,
                              void* d_out, int out_size, void* d_ws, size_t ws_size,
                              hipStream_t stream) {
  const float* enc_out = (const float*)d_in[0];
  const int*   dec_in  = (const int*)d_in[1];
  const int*   enc_in  = (const int*)d_in[2];
  const float* emb     = (const float*)d_in[3];
  const float* wq1 = (const float*)d_in[4];  const float* bq1 = (const float*)d_in[5];
  const float* wk1 = (const float*)d_in[6];  const float* bk1 = (const float*)d_in[7];
  const float* wv1 = (const float*)d_in[8];  const float* bv1 = (const float*)d_in[9];
  const float* wo1 = (const float*)d_in[10]; const float* bo1 = (const float*)d_in[11];
  const float* pos1 = (const float*)d_in[12];
  const float* wq2 = (const float*)d_in[13]; const float* bq2 = (const float*)d_in[14];
  const float* wk2 = (const float*)d_in[15]; const float* bk2 = (const float*)d_in[16];
  const float* wv2 = (const float*)d_in[17]; const float* bv2 = (const float*)d_in[18];
  const float* wo2 = (const float*)d_in[19]; const float* bo2 = (const float*)d_in[20];
  const float* ln1g = (const float*)d_in[21]; const float* ln1b = (const float*)d_in[22];
  const float* ln2g = (const float*)d_in[23]; const float* ln2b = (const float*)d_in[24];
  const float* ln3g = (const float*)d_in[25]; const float* ln3b = (const float*)d_in[26];
  const float* wf1 = (const float*)d_in[27]; const float* bf1 = (const float*)d_in[28];
  const float* wf2 = (const float*)d_in[29]; const float* bf2 = (const float*)d_in[30];
  const float* wout = (const float*)d_in[31]; const float* bout = (const float*)d_in[32];

  char* ws = (char*)d_ws;
  u16*   WT    = (u16*)(ws + 0);             // 32MB  per-layer transposed weights
  float* maskD = (float*)(ws + 33554432);    // 8KB   (region free until WoutT)
  float* maskE = (float*)(ws + 33562624);    // 8KB
  u16*   WoutT = (u16*)(ws + 0);             // 65.5MB, used only at the end
  u16*   PEP   = (u16*)(ws + 67108864);      // 32MB  PE bf16 [32768][512]
  float* X     = (float*)(ws + 100663296);   // 8MB
  float* Xa    = (float*)(ws + 109051904);   // 8MB
  float* Xb    = (float*)(ws + 117440512);   // 8MB
  float* Rb    = (float*)(ws + 125829120);   // 8MB
  u16*   Ab16  = (u16*)(ws + 134217728);     // 4MB  current GEMM-input activation
  u16*   Q     = (u16*)(ws + 138412032);     // 4MB  [g][512][64]
  u16*   Kh    = (u16*)(ws + 142606336);     // 4MB  [g][512][64]
  u16*   VT    = (u16*)(ws + 146800640);     // 8MB  [g][128][512]
  u16*   Ob16  = (u16*)(ws + 155189248);     // 4MB  merged attn out
  u16*   FFH16 = (u16*)(ws + 159383552);     // 16MB [2048][4096]
  u16*   encb  = (u16*)(ws + 176160768);     // 4MB  encoder_outputs bf16
  u16*   posb  = (u16*)(ws + 180355072);     // 384KB [6][512][64]
  float* out   = (float*)d_out;

  embed_kernel<<<2048, 256, 0, stream>>>(dec_in, emb, X, Ab16);
  conv_bf16<<<2048, 256, 0, stream>>>(enc_out, encb);
  conv_pos<<<192, 256, 0, stream>>>(pos1, posb);
  mask_kernel<<<8, 256, 0, stream>>>(dec_in, enc_in, maskD, maskE);

  for (int i = 0; i < 6; ++i) {
    const size_t oHH = (size_t)i * 1048576u, oH = (size_t)i * 1024u;
    const float* bq1i = bq1 + oH; const float* bk1i = bk1 + oH;
    const float* bv1i = bv1 + oH; const float* bo1i = bo1 + oH;
    const float* bq2i = bq2 + oH; const float* bk2i = bk2 + oH;
    const float* bv2i = bv2 + oH; const float* bo2i = bo2 + oH;
    const float* bf1i = bf1 + (size_t)i * 4096u; const float* bf2i = bf2 + oH;
    const u16* posL = posb + (size_t)i * 32768u;

    conv_layer<<<4096, 256, 0, stream>>>(
        wq1 + oHH, wk1 + oHH, wv1 + oHH, wo1 + oHH,
        wq2 + oHH, wk2 + oHH, wv2 + oHH, wo2 + oHH,
        wf1 + (size_t)i * 4194304u, wf2 + (size_t)i * 4194304u, WT);

    // ---- self attention ----
    bgemm<4, true, 4, false, false, 0, 8><<<dim3(24, 16, 1), 256, 0, stream>>>(
        Ab16, 0, WT, 0, bq1i, bk1i, bv1i, nullptr, Q, Kh, VT, 0, 0, 1024, 0.125f);
    bgemm<0, true, 4, false, false, 2, 8><<<dim3(4, 256, 1), 256, 0, stream>>>(
        Q, 0, posL, 0, nullptr, nullptr, nullptr, nullptr, PEP, nullptr, nullptr,
        0, 512, 64, 1.f);
    fused_attn<true><<<dim3(16, 64), 256, 0, stream>>>(Q, Kh, VT, PEP, maskD, Ob16);
    bgemm<0, false, 2, false, true, 0, 8><<<dim3(8, 32, 1), 256, 0, stream>>>(
        Ob16, 0, WT + 3145728u, 0, bo1i, nullptr, nullptr, X, Rb, nullptr, nullptr,
        0, 1024, 1024, 1.f);
    layernorm_kernel<<<2048, 256, 0, stream>>>(Rb, ln1g + oH, ln1b + oH, Xa, Ab16);

    // ---- cross attention ----
    bgemm<1, true, 2, false, false, 0, 8><<<dim3(8, 32, 1), 256, 0, stream>>>(
        Ab16, 0, WT + 4194304u, 0, bq2i, nullptr, nullptr, nullptr, Q, nullptr, nullptr,
        0, 0, 1024, 0.125f);
    bgemm<5, true, 4, false, false, 0, 8><<<dim3(16, 16, 1), 256, 0, stream>>>(
        encb, 0, WT + 5242880u, 0, bk2i, bv2i, nullptr, nullptr, Kh, VT, nullptr,
        0, 0, 1024, 1.f);
    fused_attn<false><<<dim3(16, 64), 256, 0, stream>>>(Q, Kh, VT, nullptr, maskE, Ob16);
    bgemm<0, false, 2, false, true, 0, 8><<<dim3(8, 32, 1), 256, 0, stream>>>(
        Ob16, 0, WT + 7340032u, 0, bo2i, nullptr, nullptr, Xa, Rb, nullptr, nullptr,
        0, 1024, 1024, 1.f);
    layernorm_kernel<<<2048, 256, 0, stream>>>(Rb, ln2g + oH, ln2b + oH, Xb, Ab16);

    // ---- FFN ----
    bgemm<0, true, 4, true, false, 0, 8><<<dim3(32, 16, 1), 256, 0, stream>>>(
        Ab16, 0, WT + 8388608u, 0, bf1i, nullptr, nullptr, nullptr, FFH16, nullptr, nullptr,
        0, 4096, 1024, 1.f);
    bgemm<0, false, 2, false, true, 0, 8><<<dim3(8, 32, 1), 256, 0, stream>>>(
        FFH16, 0, WT + 12582912u, 0, bf2i, nullptr, nullptr, Xb, Rb, nullptr, nullptr,
        0, 1024, 4096, 1.f);
    layernorm_kernel<<<2048, 256, 0, stream>>>(Rb, ln3g + oH, ln3b + oH, X, Ab16);
  }

  // ---- output head (f16 logits into d_out row-halves) + log_softmax ----
  conv_wout<<<8000, 256, 0, stream>>>(wout, WoutT);
  bgemm<6, false, 4, false, false, 0, 16><<<dim3(250, 16, 1), 256, 0, stream>>>(
      Ab16, 0, WoutT, 0, bout, nullptr, nullptr, nullptr, out, nullptr, nullptr,
      0, 64000, 1024, 1.f);
  log_softmax_kernel<<<2048, 512, 0, stream>>>(out);
}

// Round 5
// 2269.556 us; speedup vs baseline: 3.1160x; 1.0183x over previous
//
#include <hip/hip_runtime.h>

// ---------------------------------------------------------------------------
// TransformerDecoder forward on MI355X (gfx950) — round 5.
// Round-5 delta: fused attention rebuilt as barrier-free wave-independent
// kernel (wave owns 16 Q-rows end-to-end; private LDS score strip; no
// __syncthreads, no cross-wave reduce; XCD-local g mapping).
// ---------------------------------------------------------------------------

typedef unsigned short u16;
typedef short s16x8 __attribute__((ext_vector_type(8)));
typedef unsigned short u16x4 __attribute__((ext_vector_type(4)));
typedef unsigned short u16x8 __attribute__((ext_vector_type(8)));
typedef float f32x4 __attribute__((ext_vector_type(4)));

#define PADTOK 2
#define NEG_INF (-__builtin_inff())

static __device__ __forceinline__ u16 f2bf(float f) {
  unsigned u = __float_as_uint(f);
  u += 0x7fffu + ((u >> 16) & 1u);
  return (u16)(u >> 16);
}
static __device__ __forceinline__ float bf2f(u16 h) {
  return __uint_as_float(((unsigned)h) << 16);
}
static __device__ __forceinline__ float f16tof(u16 h) {
  _Float16 x = __builtin_bit_cast(_Float16, h);
  return (float)x;
}
static __device__ __forceinline__ u16 ftof16(float v) {
  _Float16 x = (_Float16)v;
  return __builtin_bit_cast(u16, x);
}
static __device__ __forceinline__ f32x4 mfma16(s16x8 a, s16x8 b, f32x4 c) {
  asm("v_mfma_f32_16x16x32_bf16 %0, %1, %2, %0" : "+v"(c) : "v"(a), "v"(b));
  return c;
}
static __device__ __forceinline__ void gll16(const void* g, void* l) {
  __builtin_amdgcn_global_load_lds((const __attribute__((address_space(1))) void*)g,
                                   (__attribute__((address_space(3))) void*)l, 16, 0, 0);
}
static __device__ __forceinline__ size_t hsidx(int m, int n) {
  return ((size_t)((m >> 9) * 16 + (n >> 6))) * 32768u + (size_t)(m & 511) * 64u + (size_t)(n & 63);
}
static __device__ __forceinline__ size_t vtidx(int m, int n) {
  return ((size_t)((m >> 9) * 16 + (n >> 6))) * 65536u + (size_t)(n & 63) * 512u + (size_t)(m & 511);
}

// XCD-chunked (bijective) + m-grouped n-major rasterization.
static __device__ __forceinline__ void raster2(int& bm, int& bn, int GM0) {
  const int nm = gridDim.y, nn = gridDim.x;
  int bid = blockIdx.y * nn + blockIdx.x;
  const int nwg = nm * nn;
  const int q = nwg >> 3, r = nwg & 7;
  const int x = bid & 7, p = bid >> 3;
  bid = (x < r ? x * (q + 1) : r * (q + 1) + (x - r) * q) + p;
  const int GM = nm < GM0 ? nm : GM0;
  const int pg = GM * nn;
  const int gi = bid / pg, rem = bid - gi * pg;
  const int left = nm - gi * GM;
  const int gm = left < GM ? left : GM;
  bm = gi * GM + rem % gm;
  bn = rem / gm;
}

// ---------------------------------------------------------------------------
// bf16 GEMM: C = epi(A[M,K] @ Bt[N,K]^T) per batch g. BM=MFR*32, BN=128, BK=64.
// EPI: 0 plain  1 headsplit  4 QKV-fused  5 KV-fused  6 f16 out
// SKIP: 0 none  2 PE band-skip
// ---------------------------------------------------------------------------
template<int EPI, bool BF16OUT, int MFR, bool RELU, bool RESID, int SKIP, int GMT>
__global__ __launch_bounds__(256)
void bgemm(const u16* __restrict__ A, long long sAg,
           const u16* __restrict__ Bt, long long sBg,
           const float* __restrict__ bias, const float* __restrict__ bias2,
           const float* __restrict__ bias3,
           const float* __restrict__ Res,
           void* __restrict__ Cv, u16* __restrict__ C2, u16* __restrict__ C3,
           long long sCg, int ldc, int K, float scale)
{
  constexpr int BM = MFR * 32;
  __shared__ u16 As[BM * 64];
  __shared__ u16 Bs[128 * 64];
  int bmi, bni;
  raster2(bmi, bni, GMT);
  const int bm0 = bmi * BM, bn0 = bni * 128;
  if constexpr (SKIP == 2) {          // PE: tile unread iff (i0&511)+n0 <= 256
    if ((bm0 & 511) + bn0 <= 256) return;
  }
  const int g = blockIdx.z;
  const u16* Ag = A + (size_t)g * (size_t)sAg;
  const u16* Bg = Bt + (size_t)g * (size_t)sBg;
  const int tid = threadIdx.x, l = tid & 63, w = tid >> 6;
  const int wm = w >> 1, wn = w & 1;
  const int rsel = l & 15, kg = l >> 4, xs = l & 7;

  f32x4 acc[MFR][4];
#pragma unroll
  for (int i = 0; i < MFR; ++i)
#pragma unroll
    for (int j = 0; j < 4; ++j) acc[i][j] = (f32x4){0.f, 0.f, 0.f, 0.f};

  const int srow = l >> 3;               // row within 8-row group
  const int sch  = (l & 7) ^ srow;       // swizzled source chunk
  const u16* Agp = Ag + ((size_t)(bm0 + w * 8 * MFR + srow)) * (size_t)K + sch * 8;
  const u16* Bgp = Bg + ((size_t)(bn0 + w * 32 + srow)) * (size_t)K + sch * 8;
  char* AsL = (char*)As + (w * 8 * MFR) * 128;
  char* BsL = (char*)Bs + (w * 32) * 128;

  for (int k0 = 0; k0 < K; k0 += 64) {
    __syncthreads();
#pragma unroll
    for (int i = 0; i < MFR; ++i)
      gll16(Agp + (size_t)i * 8 * K + k0, AsL + i * 1024);
#pragma unroll
    for (int i = 0; i < 4; ++i)
      gll16(Bgp + (size_t)i * 8 * K + k0, BsL + i * 1024);
    __syncthreads();

    const int arow0 = (wm * (MFR * 16) + rsel) * 128;
    const int brow0 = (wn * 64 + rsel) * 128;
#pragma unroll
    for (int ks = 0; ks < 2; ++ks) {
      const int ch = ((ks * 4 + kg) ^ xs) * 16;
      s16x8 af[MFR], bfr[4];
#pragma unroll
      for (int mf = 0; mf < MFR; ++mf)
        af[mf] = *(const s16x8*)((const char*)As + arow0 + mf * 2048 + ch);
#pragma unroll
      for (int nf = 0; nf < 4; ++nf)
        bfr[nf] = *(const s16x8*)((const char*)Bs + brow0 + nf * 2048 + ch);
#pragma unroll
      for (int mf = 0; mf < MFR; ++mf)
#pragma unroll
        for (int nf = 0; nf < 4; ++nf)
          acc[mf][nf] = mfma16(af[mf], bfr[nf], acc[mf][nf]);
    }
  }

  // epilogue: C/D layout col=lane&15 (n), row=(lane>>4)*4+e (m)
#pragma unroll
  for (int mf = 0; mf < MFR; ++mf) {
#pragma unroll
    for (int nf = 0; nf < 4; ++nf) {
      const int n = bn0 + wn * 64 + nf * 16 + rsel;
      int sub = 0, nl = n;
      const float* bp = bias;
      if constexpr (EPI == 4) {
        sub = n >> 10; nl = n & 1023;
        bp = (sub == 0) ? bias : (sub == 1) ? bias2 : bias3;
      }
      if constexpr (EPI == 5) {
        sub = n >> 10; nl = n & 1023;
        bp = (sub == 0) ? bias : bias2;
      }
      const float bv = bp ? bp[nl] : 0.f;
      float sc = 1.f;
      if constexpr (EPI == 0 || EPI == 1) sc = scale;
      if constexpr (EPI == 4) sc = (sub == 0) ? scale : 1.f;
#pragma unroll
      for (int e = 0; e < 4; ++e) {
        const int m = bm0 + wm * (MFR * 16) + mf * 16 + kg * 4 + e;
        float v = (acc[mf][nf][e] + bv) * sc;
        if constexpr (RELU) v = fmaxf(v, 0.f);
        if constexpr (RESID) v += Res[(size_t)m * (size_t)ldc + n];
        if constexpr (EPI == 0) {
          const size_t idx = (size_t)g * (size_t)sCg + (size_t)m * (size_t)ldc + n;
          if constexpr (BF16OUT) ((u16*)Cv)[idx] = f2bf(v);
          else                   ((float*)Cv)[idx] = v;
        } else if constexpr (EPI == 1) {
          ((u16*)Cv)[hsidx(m, nl)] = f2bf(v);
        } else if constexpr (EPI == 4) {
          if (sub == 2)      C3[vtidx(m, nl)] = f2bf(v);
          else if (sub == 1) C2[hsidx(m, nl)] = f2bf(v);
          else               ((u16*)Cv)[hsidx(m, nl)] = f2bf(v);
        } else if constexpr (EPI == 5) {
          if (sub == 0) ((u16*)Cv)[hsidx(m, nl)] = f2bf(v);
          else          C2[vtidx(m, nl)] = f2bf(v);
        } else if constexpr (EPI == 6) {
          ((u16*)Cv)[(size_t)m * (size_t)ldc + n] = ftof16(v);
        }
      }
    }
  }
}

// ---------------------------------------------------------------------------
// fused attention, wave-independent: each wave owns 16 Q-rows, full
// QK^T -> softmax -> PV privately; no block barriers. grid (8, 64), 256 thr.
// Q/K: [g][512][64] bf16. Vt: [g][128][512] (rows 0..63 = V^T). O merged.
// ---------------------------------------------------------------------------
template<bool SELF>
__global__ __launch_bounds__(256)
void fused_attn(const u16* __restrict__ Qb, const u16* __restrict__ Kb,
                const u16* __restrict__ Vt, const u16* __restrict__ PE,
                const float* __restrict__ maskf, u16* __restrict__ O)
{
  __shared__ u16 SP[4][16][520];       // per-wave score strip
  __shared__ float rsm[4][16];         // per-wave 1/rowsum
  // bid -> (g, rt) with g === bid (mod 8): all row-tiles of a head on one XCD
  const int bid = blockIdx.y * 8 + blockIdx.x;
  const int g = (bid & 7) + 8 * ((bid >> 3) & 7);
  const int rt = bid >> 6;             // 0..7
  const int b = g >> 4, h = g & 15;
  const int tid = threadIdx.x, l = tid & 63, w = tid >> 6;
  const int ti = SELF ? (w * 8 + rt) : (rt * 4 + w);   // row-tile 0..31
  const int i0 = ti * 16;
  const int CT = SELF ? (i0 + 16) : 512;
  const int rsel = l & 15, kg = l >> 4;

  const u16* Qg = Qb + (size_t)g * 32768u;
  const u16* Kg = Kb + (size_t)g * 32768u;
  const u16* Vg = Vt + (size_t)g * 65536u;
  u16 (*sp)[520] = SP[w];
  float* rs = rsm[w];

  // Q fragments: lane holds Q[i0 + (l&15)][k-chunk]
  const s16x8 qf0 = *(const s16x8*)(Qg + (size_t)(i0 + rsel) * 64u + kg * 8);
  const s16x8 qf1 = *(const s16x8*)(Qg + (size_t)(i0 + rsel) * 64u + 32 + kg * 8);

  // ---- QK^T (+ mask + skew + causal) -> SP ----
  for (int j0 = 0; j0 < CT; j0 += 16) {
    const s16x8 kf0 = *(const s16x8*)(Kg + (size_t)(j0 + rsel) * 64u + kg * 8);
    const s16x8 kf1 = *(const s16x8*)(Kg + (size_t)(j0 + rsel) * 64u + 32 + kg * 8);
    f32x4 a = {0.f, 0.f, 0.f, 0.f};
    a = mfma16(qf0, kf0, a);
    a = mfma16(qf1, kf1, a);
    const int jj = j0 + rsel;                   // output col = l&15
    const float mj = maskf[b * 512 + jj];
#pragma unroll
    for (int e = 0; e < 4; ++e) {
      const int r = kg * 4 + e;                 // local q-row (output row)
      float v = a[e] + mj;
      if constexpr (SELF) {
        const int i = i0 + r;
        if (jj > i) v = NEG_INF;
        else        v += bf2f(PE[((size_t)(g * 512 + i)) * 512u + (511 + jj - i)]);
      }
      sp[r][jj] = f2bf(v);
    }
  }
  asm volatile("s_waitcnt lgkmcnt(0)" ::: "memory");

  // ---- softmax (wave-local): 4 lanes per row ----
  const int sr = l >> 2, sub = l & 3;
  float mx = NEG_INF;
  for (int c = sub * 4; c < CT; c += 16) {
    const u16x4 h4 = *(const u16x4*)&sp[sr][c];
#pragma unroll
    for (int e = 0; e < 4; ++e) mx = fmaxf(mx, bf2f(h4[e]));
  }
  mx = fmaxf(mx, __shfl_xor(mx, 1, 64));
  mx = fmaxf(mx, __shfl_xor(mx, 2, 64));
  float sum = 0.f;
  for (int c = sub * 4; c < CT; c += 16) {
    const u16x4 h4 = *(const u16x4*)&sp[sr][c];
    const float p0 = expf(bf2f(h4[0]) - mx), p1 = expf(bf2f(h4[1]) - mx);
    const float p2 = expf(bf2f(h4[2]) - mx), p3 = expf(bf2f(h4[3]) - mx);
    sum += p0 + p1 + p2 + p3;
    const u16x4 o4 = {f2bf(p0), f2bf(p1), f2bf(p2), f2bf(p3)};
    *(u16x4*)&sp[sr][c] = o4;                  // unnormalized P
  }
  sum += __shfl_xor(sum, 1, 64);
  sum += __shfl_xor(sum, 2, 64);
  if (sub == 0) rs[sr] = 1.f / sum;
  if (CT & 31) {                               // zero-pad P to 32-col boundary
    const u16x4 z = {0, 0, 0, 0};
    *(u16x4*)&sp[sr][CT + sub * 4] = z;
  }
  asm volatile("s_waitcnt lgkmcnt(0)" ::: "memory");

  // ---- PV: O[16][64] accumulated in registers ----
  f32x4 oa[4];
#pragma unroll
  for (int nt = 0; nt < 4; ++nt) oa[nt] = (f32x4){0.f, 0.f, 0.f, 0.f};
  const int nk = (CT + 31) >> 5;
  for (int kt = 0; kt < nk; ++kt) {
    const s16x8 pf = *(const s16x8*)&sp[rsel][kt * 32 + kg * 8];
#pragma unroll
    for (int nt = 0; nt < 4; ++nt) {
      const s16x8 vf = *(const s16x8*)(Vg + (size_t)(nt * 16 + rsel) * 512u + kt * 32 + kg * 8);
      oa[nt] = mfma16(pf, vf, oa[nt]);
    }
  }

  // ---- normalize + merged-head write ----
#pragma unroll
  for (int e = 0; e < 4; ++e) {
    const int q = kg * 4 + e;                  // local row
    const float inv = rs[q];
    u16* orow = O + ((size_t)(b * 512 + i0 + q)) * 1024u + h * 64;
#pragma unroll
    for (int nt = 0; nt < 4; ++nt)
      orow[nt * 16 + rsel] = f2bf(oa[nt][e] * inv);
  }
}

// ---------------------------------------------------------------------------
// transpose+convert f32[K,N] -> bf16[N,K], 64x64 tiles
// ---------------------------------------------------------------------------
static __device__ __forceinline__ void tconv_tile(const float* in, int N,
                                                  u16* out, int K, int k0, int n0) {
  __shared__ u16 L[64][72];
  const int t = threadIdx.x;
  const int rk = t >> 4, cn = (t & 15) * 4;
#pragma unroll
  for (int q = 0; q < 4; ++q) {
    const int kk = k0 + rk + q * 16;
    float4 v = *(const float4*)(in + (size_t)kk * (size_t)N + n0 + cn);
    L[cn + 0][rk + q * 16] = f2bf(v.x);
    L[cn + 1][rk + q * 16] = f2bf(v.y);
    L[cn + 2][rk + q * 16] = f2bf(v.z);
    L[cn + 3][rk + q * 16] = f2bf(v.w);
  }
  __syncthreads();
  const int rn = t >> 2, ck = (t & 3) * 16;
  u16* op = out + (size_t)(n0 + rn) * (size_t)K + k0 + ck;
  *(s16x8*)op       = *(const s16x8*)&L[rn][ck];
  *(s16x8*)(op + 8) = *(const s16x8*)&L[rn][ck + 8];
}

__global__ __launch_bounds__(256)
void conv_layer(const float* w0, const float* w1, const float* w2, const float* w3,
                const float* w4, const float* w5, const float* w6, const float* w7,
                const float* w8, const float* w9, u16* WT) {
  const int b = blockIdx.x;
  const float* in; u16* out; int N, K, kt, nt;
  if (b < 2048) {
    const int j = b >> 8, t = b & 255;
    const float* ws[8] = {w0, w1, w2, w3, w4, w5, w6, w7};
    in = ws[j]; out = WT + (size_t)j * 1048576u; K = 1024; N = 1024;
    kt = t >> 4; nt = t & 15;
  } else if (b < 3072) {
    const int t = b - 2048;
    in = w8; out = WT + 8388608u; K = 1024; N = 4096; kt = t >> 6; nt = t & 63;
  } else {
    const int t = b - 3072;
    in = w9; out = WT + 12582912u; K = 4096; N = 1024; kt = t >> 4; nt = t & 15;
  }
  tconv_tile(in, N, out, K, kt * 64, nt * 64);
}

__global__ __launch_bounds__(256)
void conv_wout(const float* in, u16* out) {
  const int b = blockIdx.x;            // 8000 = 16 ktiles * 500 ntiles
  const int kt = b / 500, nt = b % 500;
  tconv_tile(in, 32000, out, 1024, kt * 64, nt * 64);
}

// ---------------------------------------------------------------------------
// elementwise converts / masks
// ---------------------------------------------------------------------------
__global__ void conv_bf16(const float* __restrict__ in, u16* __restrict__ out) {
  const int i = (blockIdx.x * 256 + threadIdx.x) * 4;
  float4 v = *(const float4*)(in + i);
  u16x4 h = {f2bf(v.x), f2bf(v.y), f2bf(v.z), f2bf(v.w)};
  *(u16x4*)(out + i) = h;
}

__global__ void conv_pos(const float* __restrict__ pos, u16* __restrict__ posb) {
  const int idx = (blockIdx.x * 256 + threadIdx.x) * 4;   // over 6*512*64
  const int lyr = idx >> 15, rem = idx & 32767;
  float4 v = *(const float4*)(pos + (size_t)lyr * 65472u + rem);
  u16x4 h = {f2bf(v.x), f2bf(v.y), f2bf(v.z), f2bf(v.w)};
  *(u16x4*)(posb + idx) = h;
}

__global__ void mask_kernel(const int* __restrict__ dec, const int* __restrict__ enc,
                            float* __restrict__ mD, float* __restrict__ mE) {
  const int i = blockIdx.x * 256 + threadIdx.x;   // 2048
  mD[i] = (dec[i] == PADTOK) ? NEG_INF : 0.f;
  mE[i] = (enc[i] == PADTOK) ? NEG_INF : 0.f;
}

// ---------------------------------------------------------------------------
// reductions
// ---------------------------------------------------------------------------
static __device__ __forceinline__ float wred_sum(float v) {
#pragma unroll
  for (int o = 32; o > 0; o >>= 1) v += __shfl_down(v, o, 64);
  return v;
}
static __device__ __forceinline__ float wred_max(float v) {
#pragma unroll
  for (int o = 32; o > 0; o >>= 1) v = fmaxf(v, __shfl_down(v, o, 64));
  return v;
}
static __device__ __forceinline__ float bred_sum(float v, float* sm) {
  const int lane = threadIdx.x & 63, wid = threadIdx.x >> 6;
  v = wred_sum(v);
  if (lane == 0) sm[wid] = v;
  __syncthreads();
  if (threadIdx.x == 0) sm[0] = sm[0] + sm[1] + sm[2] + sm[3];
  __syncthreads();
  const float r = sm[0];
  __syncthreads();
  return r;
}

// ---------------------------------------------------------------------------
// small kernels
// ---------------------------------------------------------------------------
__global__ void embed_kernel(const int* __restrict__ dec, const float* __restrict__ emb,
                             float* __restrict__ X, u16* __restrict__ Xh) {
  const int m = blockIdx.x, t = threadIdx.x;
  const int tok = dec[m];
  float4 v = ((const float4*)(emb + (size_t)tok * 1024u))[t];
  ((float4*)(X + (size_t)m * 1024u))[t] = v;
  u16x4 h = {f2bf(v.x), f2bf(v.y), f2bf(v.z), f2bf(v.w)};
  *(u16x4*)(Xh + (size_t)m * 1024u + t * 4) = h;
}

__global__ void layernorm_kernel(const float* __restrict__ R,
                                 const float* __restrict__ gw, const float* __restrict__ bw,
                                 float* __restrict__ Y, u16* __restrict__ Yh) {
  __shared__ float sm[4];
  const int m = blockIdx.x, t = threadIdx.x;
  float4 v = ((const float4*)(R + (size_t)m * 1024u))[t];
  float s = v.x + v.y + v.z + v.w;
  s = bred_sum(s, sm);
  const float mean = s * (1.f / 1024.f);
  const float d0 = v.x - mean, d1 = v.y - mean, d2 = v.z - mean, d3 = v.w - mean;
  float q = d0 * d0 + d1 * d1 + d2 * d2 + d3 * d3;
  q = bred_sum(q, sm);
  const float rstd = rsqrtf(q * (1.f / 1024.f) + 1e-5f);
  const int c = t * 4;
  float4 o;
  o.x = d0 * rstd * gw[c + 0] + bw[c + 0];
  o.y = d1 * rstd * gw[c + 1] + bw[c + 1];
  o.z = d2 * rstd * gw[c + 2] + bw[c + 2];
  o.w = d3 * rstd * gw[c + 3] + bw[c + 3];
  ((float4*)(Y + (size_t)m * 1024u))[t] = o;
  u16x4 h = {f2bf(o.x), f2bf(o.y), f2bf(o.z), f2bf(o.w)};
  *(u16x4*)(Yh + (size_t)m * 1024u + c) = h;
}

// log_softmax over V=32000: f16 logits live in the first half of each f32
// output row of d_out. Stage row in LDS, reduce, write f32 logprobs.
__global__ __launch_bounds__(512)
void log_softmax_kernel(float* __restrict__ out) {
  __shared__ u16 row[32000];
  __shared__ float sm[8];
  const int m = blockIdx.x, tid = threadIdx.x;
  const u16* src = (const u16*)out + (size_t)m * 64000u;
  for (int c = tid; c < 4000; c += 512)
    *(u16x8*)&row[c * 8] = *(const u16x8*)(src + c * 8);
  __syncthreads();
  float mx = NEG_INF;
  for (int c = tid; c < 4000; c += 512) {
    const u16x8 h = *(const u16x8*)&row[c * 8];
#pragma unroll
    for (int e = 0; e < 8; ++e) mx = fmaxf(mx, f16tof(h[e]));
  }
  mx = wred_max(mx);
  if ((tid & 63) == 0) sm[tid >> 6] = mx;
  __syncthreads();
  if (tid == 0) {
    float a = sm[0];
#pragma unroll
    for (int wI = 1; wI < 8; ++wI) a = fmaxf(a, sm[wI]);
    sm[0] = a;
  }
  __syncthreads();
  mx = sm[0];
  __syncthreads();
  float s = 0.f;
  for (int c = tid; c < 4000; c += 512) {
    const u16x8 h = *(const u16x8*)&row[c * 8];
#pragma unroll
    for (int e = 0; e < 8; ++e) s += expf(f16tof(h[e]) - mx);
  }
  s = wred_sum(s);
  if ((tid & 63) == 0) sm[tid >> 6] = s;
  __syncthreads();
  if (tid == 0) {
    float a = 0.f;
#pragma unroll
    for (int wI = 0; wI < 8; ++wI) a += sm[wI];
    sm[0] = a;
  }
  __syncthreads();
  const float lse = mx + logf(sm[0]);
  float* dst = out + (size_t)m * 32000u;
  for (int c = tid; c < 4000; c += 512) {
    const u16x8 h = *(const u16x8*)&row[c * 8];
    float4 o0, o1;
    o0.x = f16tof(h[0]) - lse; o0.y = f16tof(h[1]) - lse;
    o0.z = f16tof(h[2]) - lse; o0.w = f16tof(h[3]) - lse;
    o1.x = f16tof(h[4]) - lse; o1.y = f16tof(h[5]) - lse;
    o1.z = f16tof(h[6]) - lse; o1.w = f16tof(h[7]) - lse;
    ((float4*)dst)[c * 2]     = o0;
    ((float4*)dst)[c * 2 + 1] = o1;
  }
}

// ---------------------------------------------------------------------------
// host driver
// ---------------------------------------------------------------------------
extern "C" void kernel_launch(void* const* d_in, const int* in_sizes, int n_in,
                              void* d_out, int out_size, void* d_ws, size_t ws_size,
                              hipStream_t stream) {
  const float* enc_out = (const float*)d_in[0];
  const int*   dec_in  = (const int*)d_in[1];
  const int*   enc_in  = (const int*)d_in[2];
  const float* emb     = (const float*)d_in[3];
  const float* wq1 = (const float*)d_in[4];  const float* bq1 = (const float*)d_in[5];
  const float* wk1 = (const float*)d_in[6];  const float* bk1 = (const float*)d_in[7];
  const float* wv1 = (const float*)d_in[8];  const float* bv1 = (const float*)d_in[9];
  const float* wo1 = (const float*)d_in[10]; const float* bo1 = (const float*)d_in[11];
  const float* pos1 = (const float*)d_in[12];
  const float* wq2 = (const float*)d_in[13]; const float* bq2 = (const float*)d_in[14];
  const float* wk2 = (const float*)d_in[15]; const float* bk2 = (const float*)d_in[16];
  const float* wv2 = (const float*)d_in[17]; const float* bv2 = (const float*)d_in[18];
  const float* wo2 = (const float*)d_in[19]; const float* bo2 = (const float*)d_in[20];
  const float* ln1g = (const float*)d_in[21]; const float* ln1b = (const float*)d_in[22];
  const float* ln2g = (const float*)d_in[23]; const float* ln2b = (const float*)d_in[24];
  const float* ln3g = (const float*)d_in[25]; const float* ln3b = (const float*)d_in[26];
  const float* wf1 = (const float*)d_in[27]; const float* bf1 = (const float*)d_in[28];
  const float* wf2 = (const float*)d_in[29]; const float* bf2 = (const float*)d_in[30];
  const float* wout = (const float*)d_in[31]; const float* bout = (const float*)d_in[32];

  char* ws = (char*)d_ws;
  u16*   WT    = (u16*)(ws + 0);             // 32MB  per-layer transposed weights
  float* maskD = (float*)(ws + 33554432);    // 8KB   (region free until WoutT)
  float* maskE = (float*)(ws + 33562624);    // 8KB
  u16*   WoutT = (u16*)(ws + 0);             // 65.5MB, used only at the end
  u16*   PEP   = (u16*)(ws + 67108864);      // 32MB  PE bf16 [32768][512]
  float* X     = (float*)(ws + 100663296);   // 8MB
  float* Xa    = (float*)(ws + 109051904);   // 8MB
  float* Xb    = (float*)(ws + 117440512);   // 8MB
  float* Rb    = (float*)(ws + 125829120);   // 8MB
  u16*   Ab16  = (u16*)(ws + 134217728);     // 4MB  current GEMM-input activation
  u16*   Q     = (u16*)(ws + 138412032);     // 4MB  [g][512][64]
  u16*   Kh    = (u16*)(ws + 142606336);     // 4MB  [g][512][64]
  u16*   VT    = (u16*)(ws + 146800640);     // 8MB  [g][128][512]
  u16*   Ob16  = (u16*)(ws + 155189248);     // 4MB  merged attn out
  u16*   FFH16 = (u16*)(ws + 159383552);     // 16MB [2048][4096]
  u16*   encb  = (u16*)(ws + 176160768);     // 4MB  encoder_outputs bf16
  u16*   posb  = (u16*)(ws + 180355072);     // 384KB [6][512][64]
  float* out   = (float*)d_out;

  embed_kernel<<<2048, 256, 0, stream>>>(dec_in, emb, X, Ab16);
  conv_bf16<<<2048, 256, 0, stream>>>(enc_out, encb);
  conv_pos<<<192, 256, 0, stream>>>(pos1, posb);
  mask_kernel<<<8, 256, 0, stream>>>(dec_in, enc_in, maskD, maskE);

  for (int i = 0; i < 6; ++i) {
    const size_t oHH = (size_t)i * 1048576u, oH = (size_t)i * 1024u;
    const float* bq1i = bq1 + oH; const float* bk1i = bk1 + oH;
    const float* bv1i = bv1 + oH; const float* bo1i = bo1 + oH;
    const float* bq2i = bq2 + oH; const float* bk2i = bk2 + oH;
    const float* bv2i = bv2 + oH; const float* bo2i = bo2 + oH;
    const float* bf1i = bf1 + (size_t)i * 4096u; const float* bf2i = bf2 + oH;
    const u16* posL = posb + (size_t)i * 32768u;

    conv_layer<<<4096, 256, 0, stream>>>(
        wq1 + oHH, wk1 + oHH, wv1 + oHH, wo1 + oHH,
        wq2 + oHH, wk2 + oHH, wv2 + oHH, wo2 + oHH,
        wf1 + (size_t)i * 4194304u, wf2 + (size_t)i * 4194304u, WT);

    // ---- self attention ----
    bgemm<4, true, 4, false, false, 0, 8><<<dim3(24, 16, 1), 256, 0, stream>>>(
        Ab16, 0, WT, 0, bq1i, bk1i, bv1i, nullptr, Q, Kh, VT, 0, 0, 1024, 0.125f);
    bgemm<0, true, 4, false, false, 2, 8><<<dim3(4, 256, 1), 256, 0, stream>>>(
        Q, 0, posL, 0, nullptr, nullptr, nullptr, nullptr, PEP, nullptr, nullptr,
        0, 512, 64, 1.f);
    fused_attn<true><<<dim3(8, 64), 256, 0, stream>>>(Q, Kh, VT, PEP, maskD, Ob16);
    bgemm<0, false, 2, false, true, 0, 8><<<dim3(8, 32, 1), 256, 0, stream>>>(
        Ob16, 0, WT + 3145728u, 0, bo1i, nullptr, nullptr, X, Rb, nullptr, nullptr,
        0, 1024, 1024, 1.f);
    layernorm_kernel<<<2048, 256, 0, stream>>>(Rb, ln1g + oH, ln1b + oH, Xa, Ab16);

    // ---- cross attention ----
    bgemm<1, true, 2, false, false, 0, 8><<<dim3(8, 32, 1), 256, 0, stream>>>(
        Ab16, 0, WT + 4194304u, 0, bq2i, nullptr, nullptr, nullptr, Q, nullptr, nullptr,
        0, 0, 1024, 0.125f);
    bgemm<5, true, 4, false, false, 0, 8><<<dim3(16, 16, 1), 256, 0, stream>>>(
        encb, 0, WT + 5242880u, 0, bk2i, bv2i, nullptr, nullptr, Kh, VT, nullptr,
        0, 0, 1024, 1.f);
    fused_attn<false><<<dim3(8, 64), 256, 0, stream>>>(Q, Kh, VT, nullptr, maskE, Ob16);
    bgemm<0, false, 2, false, true, 0, 8><<<dim3(8, 32, 1), 256, 0, stream>>>(
        Ob16, 0, WT + 7340032u, 0, bo2i, nullptr, nullptr, Xa, Rb, nullptr, nullptr,
        0, 1024, 1024, 1.f);
    layernorm_kernel<<<2048, 256, 0, stream>>>(Rb, ln2g + oH, ln2b + oH, Xb, Ab16);

    // ---- FFN ----
    bgemm<0, true, 4, true, false, 0, 8><<<dim3(32, 16, 1), 256, 0, stream>>>(
        Ab16, 0, WT + 8388608u, 0, bf1i, nullptr, nullptr, nullptr, FFH16, nullptr, nullptr,
        0, 4096, 1024, 1.f);
    bgemm<0, false, 2, false, true, 0, 8><<<dim3(8, 32, 1), 256, 0, stream>>>(
        FFH16, 0, WT + 12582912u, 0, bf2i, nullptr, nullptr, Xb, Rb, nullptr, nullptr,
        0, 1024, 4096, 1.f);
    layernorm_kernel<<<2048, 256, 0, stream>>>(Rb, ln3g + oH, ln3b + oH, X, Ab16);
  }

  // ---- output head (f16 logits into d_out row-halves) + log_softmax ----
  conv_wout<<<8000, 256, 0, stream>>>(wout, WoutT);
  bgemm<6, false, 4, false, false, 0, 16><<<dim3(250, 16, 1), 256, 0, stream>>>(
      Ab16, 0, WoutT, 0, bout, nullptr, nullptr, nullptr, out, nullptr, nullptr,
      0, 64000, 1024, 1.f);
  log_softmax_kernel<<<2048, 512, 0, stream>>>(out);
}

// Round 7
// 2079.937 us; speedup vs baseline: 3.4001x; 1.0912x over previous
//
#include <hip/hip_runtime.h>

// ---------------------------------------------------------------------------
// TransformerDecoder forward on MI355X (gfx950) — round 7.
// Round-7: bisect of round-6 failure. KEEP split-K out-proj/FFN2 + fused
// lnred (reduce+bias+residual+LN). REVERT q2kv2 merge and fattn setprio to
// round-5 proven forms. Add sched_barrier(0) after fattn lgkmcnt fences.
// ---------------------------------------------------------------------------

typedef unsigned short u16;
typedef short s16x8 __attribute__((ext_vector_type(8)));
typedef unsigned short u16x4 __attribute__((ext_vector_type(4)));
typedef unsigned short u16x8 __attribute__((ext_vector_type(8)));
typedef float f32x4 __attribute__((ext_vector_type(4)));

#define PADTOK 2
#define NEG_INF (-__builtin_inff())

static __device__ __forceinline__ u16 f2bf(float f) {
  unsigned u = __float_as_uint(f);
  u += 0x7fffu + ((u >> 16) & 1u);
  return (u16)(u >> 16);
}
static __device__ __forceinline__ float bf2f(u16 h) {
  return __uint_as_float(((unsigned)h) << 16);
}
static __device__ __forceinline__ float f16tof(u16 h) {
  _Float16 x = __builtin_bit_cast(_Float16, h);
  return (float)x;
}
static __device__ __forceinline__ u16 ftof16(float v) {
  _Float16 x = (_Float16)v;
  return __builtin_bit_cast(u16, x);
}
static __device__ __forceinline__ f32x4 mfma16(s16x8 a, s16x8 b, f32x4 c) {
  asm("v_mfma_f32_16x16x32_bf16 %0, %1, %2, %0" : "+v"(c) : "v"(a), "v"(b));
  return c;
}
static __device__ __forceinline__ void gll16(const void* g, void* l) {
  __builtin_amdgcn_global_load_lds((const __attribute__((address_space(1))) void*)g,
                                   (__attribute__((address_space(3))) void*)l, 16, 0, 0);
}
static __device__ __forceinline__ size_t hsidx(int m, int n) {
  return ((size_t)((m >> 9) * 16 + (n >> 6))) * 32768u + (size_t)(m & 511) * 64u + (size_t)(n & 63);
}
static __device__ __forceinline__ size_t vtidx(int m, int n) {
  return ((size_t)((m >> 9) * 16 + (n >> 6))) * 65536u + (size_t)(n & 63) * 512u + (size_t)(m & 511);
}

// XCD-chunked (bijective) + m-grouped n-major rasterization.
static __device__ __forceinline__ void raster2(int& bm, int& bn, int GM0) {
  const int nm = gridDim.y, nn = gridDim.x;
  int bid = blockIdx.y * nn + blockIdx.x;
  const int nwg = nm * nn;
  const int q = nwg >> 3, r = nwg & 7;
  const int x = bid & 7, p = bid >> 3;
  bid = (x < r ? x * (q + 1) : r * (q + 1) + (x - r) * q) + p;
  const int GM = nm < GM0 ? nm : GM0;
  const int pg = GM * nn;
  const int gi = bid / pg, rem = bid - gi * pg;
  const int left = nm - gi * GM;
  const int gm = left < GM ? left : GM;
  bm = gi * GM + rem % gm;
  bn = rem / gm;
}

// ---------------------------------------------------------------------------
// bf16 GEMM: C = epi(A[M,K] @ Bt[N,K]^T). BM=MFR*32, BN=128, BK=64.
// EPI: 0 plain  1 headsplit  4 QKV-fused  5 KV-fused  6 f16 out
// SKIP: 0 none  2 PE band-skip.  KSPLIT>1: blockIdx.z = k-slice.
// ---------------------------------------------------------------------------
template<int EPI, bool BF16OUT, int MFR, bool RELU, bool RESID, int SKIP, int GMT, int KSPLIT>
__global__ __launch_bounds__(256)
void bgemm(const u16* __restrict__ A, long long sAg,
           const u16* __restrict__ Bt, long long sBg,
           const float* __restrict__ bias, const float* __restrict__ bias2,
           const float* __restrict__ bias3,
           const float* __restrict__ Res,
           void* __restrict__ Cv, u16* __restrict__ C2, u16* __restrict__ C3,
           long long sCg, int ldc, int K, float scale)
{
  constexpr int BM = MFR * 32;
  __shared__ u16 As[BM * 64];
  __shared__ u16 Bs[128 * 64];
  int bmi, bni;
  raster2(bmi, bni, GMT);
  const int bm0 = bmi * BM, bn0 = bni * 128;
  if constexpr (SKIP == 2) {          // PE: tile unread iff (i0&511)+n0 <= 256
    if ((bm0 & 511) + bn0 <= 256) return;
  }
  const int gz = blockIdx.z;
  const int g = (KSPLIT > 1) ? 0 : gz;
  const int klen = K / KSPLIT;
  const int kbase = (KSPLIT > 1) ? gz * klen : 0;
  const u16* Ag = A + (size_t)g * (size_t)sAg;
  const u16* Bg = Bt + (size_t)g * (size_t)sBg;
  const int tid = threadIdx.x, l = tid & 63, w = tid >> 6;
  const int wm = w >> 1, wn = w & 1;
  const int rsel = l & 15, kg = l >> 4, xs = l & 7;

  f32x4 acc[MFR][4];
#pragma unroll
  for (int i = 0; i < MFR; ++i)
#pragma unroll
    for (int j = 0; j < 4; ++j) acc[i][j] = (f32x4){0.f, 0.f, 0.f, 0.f};

  const int srow = l >> 3;               // row within 8-row group
  const int sch  = (l & 7) ^ srow;       // swizzled source chunk
  const u16* Agp = Ag + ((size_t)(bm0 + w * 8 * MFR + srow)) * (size_t)K + sch * 8;
  const u16* Bgp = Bg + ((size_t)(bn0 + w * 32 + srow)) * (size_t)K + sch * 8;
  char* AsL = (char*)As + (w * 8 * MFR) * 128;
  char* BsL = (char*)Bs + (w * 32) * 128;

  for (int k0 = kbase; k0 < kbase + klen; k0 += 64) {
    __syncthreads();
#pragma unroll
    for (int i = 0; i < MFR; ++i)
      gll16(Agp + (size_t)i * 8 * K + k0, AsL + i * 1024);
#pragma unroll
    for (int i = 0; i < 4; ++i)
      gll16(Bgp + (size_t)i * 8 * K + k0, BsL + i * 1024);
    __syncthreads();

    const int arow0 = (wm * (MFR * 16) + rsel) * 128;
    const int brow0 = (wn * 64 + rsel) * 128;
#pragma unroll
    for (int ks = 0; ks < 2; ++ks) {
      const int ch = ((ks * 4 + kg) ^ xs) * 16;
      s16x8 af[MFR], bfr[4];
#pragma unroll
      for (int mf = 0; mf < MFR; ++mf)
        af[mf] = *(const s16x8*)((const char*)As + arow0 + mf * 2048 + ch);
#pragma unroll
      for (int nf = 0; nf < 4; ++nf)
        bfr[nf] = *(const s16x8*)((const char*)Bs + brow0 + nf * 2048 + ch);
#pragma unroll
      for (int mf = 0; mf < MFR; ++mf)
#pragma unroll
        for (int nf = 0; nf < 4; ++nf)
          acc[mf][nf] = mfma16(af[mf], bfr[nf], acc[mf][nf]);
    }
  }

  // epilogue: C/D layout col=lane&15 (n), row=(lane>>4)*4+e (m)
#pragma unroll
  for (int mf = 0; mf < MFR; ++mf) {
#pragma unroll
    for (int nf = 0; nf < 4; ++nf) {
      const int n = bn0 + wn * 64 + nf * 16 + rsel;
      int sub = 0, nl = n;
      const float* bp = bias;
      if constexpr (EPI == 4) {
        sub = n >> 10; nl = n & 1023;
        bp = (sub == 0) ? bias : (sub == 1) ? bias2 : bias3;
      }
      if constexpr (EPI == 5) {
        sub = n >> 10; nl = n & 1023;
        bp = (sub == 0) ? bias : bias2;
      }
      const float bv = bp ? bp[nl] : 0.f;
      float sc = 1.f;
      if constexpr (EPI == 0 || EPI == 1) sc = scale;
      if constexpr (EPI == 4) sc = (sub == 0) ? scale : 1.f;
#pragma unroll
      for (int e = 0; e < 4; ++e) {
        const int m = bm0 + wm * (MFR * 16) + mf * 16 + kg * 4 + e;
        float v = (acc[mf][nf][e] + bv) * sc;
        if constexpr (RELU) v = fmaxf(v, 0.f);
        if constexpr (RESID) v += Res[(size_t)m * (size_t)ldc + n];
        if constexpr (EPI == 0) {
          const size_t idx = (size_t)gz * (size_t)sCg + (size_t)m * (size_t)ldc + n;
          if constexpr (BF16OUT) ((u16*)Cv)[idx] = f2bf(v);
          else                   ((float*)Cv)[idx] = v;
        } else if constexpr (EPI == 1) {
          ((u16*)Cv)[hsidx(m, nl)] = f2bf(v);
        } else if constexpr (EPI == 4) {
          if (sub == 2)      C3[vtidx(m, nl)] = f2bf(v);
          else if (sub == 1) C2[hsidx(m, nl)] = f2bf(v);
          else               ((u16*)Cv)[hsidx(m, nl)] = f2bf(v);
        } else if constexpr (EPI == 5) {
          if (sub == 0) ((u16*)Cv)[hsidx(m, nl)] = f2bf(v);
          else          C2[vtidx(m, nl)] = f2bf(v);
        } else if constexpr (EPI == 6) {
          ((u16*)Cv)[(size_t)m * (size_t)ldc + n] = ftof16(v);
        }
      }
    }
  }
}

// ---------------------------------------------------------------------------
// fused attention, wave-independent — round-5 proven form (NO setprio),
// plus sched_barrier(0) hardening after the lgkmcnt fences.
// ---------------------------------------------------------------------------
template<bool SELF>
__global__ __launch_bounds__(256)
void fused_attn(const u16* __restrict__ Qb, const u16* __restrict__ Kb,
                const u16* __restrict__ Vt, const u16* __restrict__ PE,
                const float* __restrict__ maskf, u16* __restrict__ O)
{
  __shared__ u16 SP[4][16][520];       // per-wave score strip
  __shared__ float rsm[4][16];         // per-wave 1/rowsum
  const int bid = blockIdx.y * 8 + blockIdx.x;
  const int g = (bid & 7) + 8 * ((bid >> 3) & 7);
  const int rt = bid >> 6;             // 0..7
  const int b = g >> 4, h = g & 15;
  const int tid = threadIdx.x, l = tid & 63, w = tid >> 6;
  const int ti = SELF ? (w * 8 + rt) : (rt * 4 + w);   // row-tile 0..31
  const int i0 = ti * 16;
  const int CT = SELF ? (i0 + 16) : 512;
  const int rsel = l & 15, kg = l >> 4;

  const u16* Qg = Qb + (size_t)g * 32768u;
  const u16* Kg = Kb + (size_t)g * 32768u;
  const u16* Vg = Vt + (size_t)g * 65536u;
  u16 (*sp)[520] = SP[w];
  float* rs = rsm[w];

  const s16x8 qf0 = *(const s16x8*)(Qg + (size_t)(i0 + rsel) * 64u + kg * 8);
  const s16x8 qf1 = *(const s16x8*)(Qg + (size_t)(i0 + rsel) * 64u + 32 + kg * 8);

  // ---- QK^T (+ mask + skew + causal) -> SP ----
  for (int j0 = 0; j0 < CT; j0 += 16) {
    const s16x8 kf0 = *(const s16x8*)(Kg + (size_t)(j0 + rsel) * 64u + kg * 8);
    const s16x8 kf1 = *(const s16x8*)(Kg + (size_t)(j0 + rsel) * 64u + 32 + kg * 8);
    f32x4 a = {0.f, 0.f, 0.f, 0.f};
    a = mfma16(qf0, kf0, a);
    a = mfma16(qf1, kf1, a);
    const int jj = j0 + rsel;                   // output col = l&15
    const float mj = maskf[b * 512 + jj];
#pragma unroll
    for (int e = 0; e < 4; ++e) {
      const int r = kg * 4 + e;                 // local q-row (output row)
      float v = a[e] + mj;
      if constexpr (SELF) {
        const int i = i0 + r;
        if (jj > i) v = NEG_INF;
        else        v += bf2f(PE[((size_t)(g * 512 + i)) * 512u + (511 + jj - i)]);
      }
      sp[r][jj] = f2bf(v);
    }
  }
  asm volatile("s_waitcnt lgkmcnt(0)" ::: "memory");
  __builtin_amdgcn_sched_barrier(0);

  // ---- softmax (wave-local): 4 lanes per row ----
  const int sr = l >> 2, sub = l & 3;
  float mx = NEG_INF;
  for (int c = sub * 4; c < CT; c += 16) {
    const u16x4 h4 = *(const u16x4*)&sp[sr][c];
#pragma unroll
    for (int e = 0; e < 4; ++e) mx = fmaxf(mx, bf2f(h4[e]));
  }
  mx = fmaxf(mx, __shfl_xor(mx, 1, 64));
  mx = fmaxf(mx, __shfl_xor(mx, 2, 64));
  float sum = 0.f;
  for (int c = sub * 4; c < CT; c += 16) {
    const u16x4 h4 = *(const u16x4*)&sp[sr][c];
    const float p0 = expf(bf2f(h4[0]) - mx), p1 = expf(bf2f(h4[1]) - mx);
    const float p2 = expf(bf2f(h4[2]) - mx), p3 = expf(bf2f(h4[3]) - mx);
    sum += p0 + p1 + p2 + p3;
    const u16x4 o4 = {f2bf(p0), f2bf(p1), f2bf(p2), f2bf(p3)};
    *(u16x4*)&sp[sr][c] = o4;                  // unnormalized P
  }
  sum += __shfl_xor(sum, 1, 64);
  sum += __shfl_xor(sum, 2, 64);
  if (sub == 0) rs[sr] = 1.f / sum;
  if (CT & 31) {                               // zero-pad P to 32-col boundary
    const u16x4 z = {0, 0, 0, 0};
    *(u16x4*)&sp[sr][CT + sub * 4] = z;
  }
  asm volatile("s_waitcnt lgkmcnt(0)" ::: "memory");
  __builtin_amdgcn_sched_barrier(0);

  // ---- PV: O[16][64] accumulated in registers ----
  f32x4 oa[4];
#pragma unroll
  for (int nt = 0; nt < 4; ++nt) oa[nt] = (f32x4){0.f, 0.f, 0.f, 0.f};
  const int nk = (CT + 31) >> 5;
  for (int kt = 0; kt < nk; ++kt) {
    const s16x8 pf = *(const s16x8*)&sp[rsel][kt * 32 + kg * 8];
#pragma unroll
    for (int nt = 0; nt < 4; ++nt) {
      const s16x8 vf = *(const s16x8*)(Vg + (size_t)(nt * 16 + rsel) * 512u + kt * 32 + kg * 8);
      oa[nt] = mfma16(pf, vf, oa[nt]);
    }
  }

  // ---- normalize + merged-head write ----
#pragma unroll
  for (int e = 0; e < 4; ++e) {
    const int q = kg * 4 + e;                  // local row
    const float inv = rs[q];
    u16* orow = O + ((size_t)(b * 512 + i0 + q)) * 1024u + h * 64;
#pragma unroll
    for (int nt = 0; nt < 4; ++nt)
      orow[nt * 16 + rsel] = f2bf(oa[nt][e] * inv);
  }
}

// ---------------------------------------------------------------------------
// split-K reduce + bias + residual + LayerNorm + bf16 copy (one row/block)
// ---------------------------------------------------------------------------
template<int KS>
__global__ __launch_bounds__(256)
void lnred_kernel(const float* __restrict__ P, const float* __restrict__ bias,
                  const float* __restrict__ R,
                  const float* __restrict__ gw, const float* __restrict__ bw,
                  float* __restrict__ Y, u16* __restrict__ Yh)
{
  __shared__ float sm[4];
  const int m = blockIdx.x, t = threadIdx.x, c = t * 4;
  float4 v = *(const float4*)(R + (size_t)m * 1024u + c);
  const float4 bb = *(const float4*)(bias + c);
  v.x += bb.x; v.y += bb.y; v.z += bb.z; v.w += bb.w;
#pragma unroll
  for (int s = 0; s < KS; ++s) {
    const float4 p = *(const float4*)(P + (size_t)s * 2097152u + (size_t)m * 1024u + c);
    v.x += p.x; v.y += p.y; v.z += p.z; v.w += p.w;
  }
  float srow = v.x + v.y + v.z + v.w;
  {  // block reduce sum
    const int lane = t & 63, wid = t >> 6;
    float r = srow;
#pragma unroll
    for (int o = 32; o > 0; o >>= 1) r += __shfl_down(r, o, 64);
    if (lane == 0) sm[wid] = r;
    __syncthreads();
    if (t == 0) sm[0] = sm[0] + sm[1] + sm[2] + sm[3];
    __syncthreads();
    srow = sm[0];
    __syncthreads();
  }
  const float mean = srow * (1.f / 1024.f);
  const float d0 = v.x - mean, d1 = v.y - mean, d2 = v.z - mean, d3 = v.w - mean;
  float q = d0 * d0 + d1 * d1 + d2 * d2 + d3 * d3;
  {
    const int lane = t & 63, wid = t >> 6;
    float r = q;
#pragma unroll
    for (int o = 32; o > 0; o >>= 1) r += __shfl_down(r, o, 64);
    if (lane == 0) sm[wid] = r;
    __syncthreads();
    if (t == 0) sm[0] = sm[0] + sm[1] + sm[2] + sm[3];
    __syncthreads();
    q = sm[0];
    __syncthreads();
  }
  const float rstd = rsqrtf(q * (1.f / 1024.f) + 1e-5f);
  float4 o;
  o.x = d0 * rstd * gw[c + 0] + bw[c + 0];
  o.y = d1 * rstd * gw[c + 1] + bw[c + 1];
  o.z = d2 * rstd * gw[c + 2] + bw[c + 2];
  o.w = d3 * rstd * gw[c + 3] + bw[c + 3];
  *(float4*)(Y + (size_t)m * 1024u + c) = o;
  const u16x4 h = {f2bf(o.x), f2bf(o.y), f2bf(o.z), f2bf(o.w)};
  *(u16x4*)(Yh + (size_t)m * 1024u + c) = h;
}

// ---------------------------------------------------------------------------
// transpose+convert f32[K,N] -> bf16[N,K], 64x64 tiles
// ---------------------------------------------------------------------------
static __device__ __forceinline__ void tconv_tile(const float* in, int N,
                                                  u16* out, int K, int k0, int n0) {
  __shared__ u16 L[64][72];
  const int t = threadIdx.x;
  const int rk = t >> 4, cn = (t & 15) * 4;
#pragma unroll
  for (int q = 0; q < 4; ++q) {
    const int kk = k0 + rk + q * 16;
    float4 v = *(const float4*)(in + (size_t)kk * (size_t)N + n0 + cn);
    L[cn + 0][rk + q * 16] = f2bf(v.x);
    L[cn + 1][rk + q * 16] = f2bf(v.y);
    L[cn + 2][rk + q * 16] = f2bf(v.z);
    L[cn + 3][rk + q * 16] = f2bf(v.w);
  }
  __syncthreads();
  const int rn = t >> 2, ck = (t & 3) * 16;
  u16* op = out + (size_t)(n0 + rn) * (size_t)K + k0 + ck;
  *(s16x8*)op       = *(const s16x8*)&L[rn][ck];
  *(s16x8*)(op + 8) = *(const s16x8*)&L[rn][ck + 8];
}

__global__ __launch_bounds__(256)
void conv_layer(const float* w0, const float* w1, const float* w2, const float* w3,
                const float* w4, const float* w5, const float* w6, const float* w7,
                const float* w8, const float* w9, u16* WT) {
  const int b = blockIdx.x;
  const float* in; u16* out; int N, K, kt, nt;
  if (b < 2048) {
    const int j = b >> 8, t = b & 255;
    const float* ws[8] = {w0, w1, w2, w3, w4, w5, w6, w7};
    in = ws[j]; out = WT + (size_t)j * 1048576u; K = 1024; N = 1024;
    kt = t >> 4; nt = t & 15;
  } else if (b < 3072) {
    const int t = b - 2048;
    in = w8; out = WT + 8388608u; K = 1024; N = 4096; kt = t >> 6; nt = t & 63;
  } else {
    const int t = b - 3072;
    in = w9; out = WT + 12582912u; K = 4096; N = 1024; kt = t >> 4; nt = t & 15;
  }
  tconv_tile(in, N, out, K, kt * 64, nt * 64);
}

__global__ __launch_bounds__(256)
void conv_wout(const float* in, u16* out) {
  const int b = blockIdx.x;            // 8000 = 16 ktiles * 500 ntiles
  const int kt = b / 500, nt = b % 500;
  tconv_tile(in, 32000, out, 1024, kt * 64, nt * 64);
}

// ---------------------------------------------------------------------------
// elementwise converts / masks
// ---------------------------------------------------------------------------
__global__ void conv_bf16(const float* __restrict__ in, u16* __restrict__ out) {
  const int i = (blockIdx.x * 256 + threadIdx.x) * 4;
  float4 v = *(const float4*)(in + i);
  u16x4 h = {f2bf(v.x), f2bf(v.y), f2bf(v.z), f2bf(v.w)};
  *(u16x4*)(out + i) = h;
}

__global__ void conv_pos(const float* __restrict__ pos, u16* __restrict__ posb) {
  const int idx = (blockIdx.x * 256 + threadIdx.x) * 4;   // over 6*512*64
  const int lyr = idx >> 15, rem = idx & 32767;
  float4 v = *(const float4*)(pos + (size_t)lyr * 65472u + rem);
  u16x4 h = {f2bf(v.x), f2bf(v.y), f2bf(v.z), f2bf(v.w)};
  *(u16x4*)(posb + idx) = h;
}

__global__ void mask_kernel(const int* __restrict__ dec, const int* __restrict__ enc,
                            float* __restrict__ mD, float* __restrict__ mE) {
  const int i = blockIdx.x * 256 + threadIdx.x;   // 2048
  mD[i] = (dec[i] == PADTOK) ? NEG_INF : 0.f;
  mE[i] = (enc[i] == PADTOK) ? NEG_INF : 0.f;
}

// ---------------------------------------------------------------------------
// reductions
// ---------------------------------------------------------------------------
static __device__ __forceinline__ float wred_sum(float v) {
#pragma unroll
  for (int o = 32; o > 0; o >>= 1) v += __shfl_down(v, o, 64);
  return v;
}
static __device__ __forceinline__ float wred_max(float v) {
#pragma unroll
  for (int o = 32; o > 0; o >>= 1) v = fmaxf(v, __shfl_down(v, o, 64));
  return v;
}

// ---------------------------------------------------------------------------
// small kernels
// ---------------------------------------------------------------------------
__global__ void embed_kernel(const int* __restrict__ dec, const float* __restrict__ emb,
                             float* __restrict__ X, u16* __restrict__ Xh) {
  const int m = blockIdx.x, t = threadIdx.x;
  const int tok = dec[m];
  float4 v = ((const float4*)(emb + (size_t)tok * 1024u))[t];
  ((float4*)(X + (size_t)m * 1024u))[t] = v;
  u16x4 h = {f2bf(v.x), f2bf(v.y), f2bf(v.z), f2bf(v.w)};
  *(u16x4*)(Xh + (size_t)m * 1024u + t * 4) = h;
}

// log_softmax over V=32000: f16 logits in first half of each f32 out row.
__global__ __launch_bounds__(512)
void log_softmax_kernel(float* __restrict__ out) {
  __shared__ u16 row[32000];
  __shared__ float sm[8];
  const int m = blockIdx.x, tid = threadIdx.x;
  const u16* src = (const u16*)out + (size_t)m * 64000u;
  for (int c = tid; c < 4000; c += 512)
    *(u16x8*)&row[c * 8] = *(const u16x8*)(src + c * 8);
  __syncthreads();
  float mx = NEG_INF;
  for (int c = tid; c < 4000; c += 512) {
    const u16x8 h = *(const u16x8*)&row[c * 8];
#pragma unroll
    for (int e = 0; e < 8; ++e) mx = fmaxf(mx, f16tof(h[e]));
  }
  mx = wred_max(mx);
  if ((tid & 63) == 0) sm[tid >> 6] = mx;
  __syncthreads();
  if (tid == 0) {
    float a = sm[0];
#pragma unroll
    for (int wI = 1; wI < 8; ++wI) a = fmaxf(a, sm[wI]);
    sm[0] = a;
  }
  __syncthreads();
  mx = sm[0];
  __syncthreads();
  float s = 0.f;
  for (int c = tid; c < 4000; c += 512) {
    const u16x8 h = *(const u16x8*)&row[c * 8];
#pragma unroll
    for (int e = 0; e < 8; ++e) s += expf(f16tof(h[e]) - mx);
  }
  s = wred_sum(s);
  if ((tid & 63) == 0) sm[tid >> 6] = s;
  __syncthreads();
  if (tid == 0) {
    float a = 0.f;
#pragma unroll
    for (int wI = 0; wI < 8; ++wI) a += sm[wI];
    sm[0] = a;
  }
  __syncthreads();
  const float lse = mx + logf(sm[0]);
  float* dst = out + (size_t)m * 32000u;
  for (int c = tid; c < 4000; c += 512) {
    const u16x8 h = *(const u16x8*)&row[c * 8];
    float4 o0, o1;
    o0.x = f16tof(h[0]) - lse; o0.y = f16tof(h[1]) - lse;
    o0.z = f16tof(h[2]) - lse; o0.w = f16tof(h[3]) - lse;
    o1.x = f16tof(h[4]) - lse; o1.y = f16tof(h[5]) - lse;
    o1.z = f16tof(h[6]) - lse; o1.w = f16tof(h[7]) - lse;
    ((float4*)dst)[c * 2]     = o0;
    ((float4*)dst)[c * 2 + 1] = o1;
  }
}

// ---------------------------------------------------------------------------
// host driver
// ---------------------------------------------------------------------------
extern "C" void kernel_launch(void* const* d_in, const int* in_sizes, int n_in,
                              void* d_out, int out_size, void* d_ws, size_t ws_size,
                              hipStream_t stream) {
  const float* enc_out = (const float*)d_in[0];
  const int*   dec_in  = (const int*)d_in[1];
  const int*   enc_in  = (const int*)d_in[2];
  const float* emb     = (const float*)d_in[3];
  const float* wq1 = (const float*)d_in[4];  const float* bq1 = (const float*)d_in[5];
  const float* wk1 = (const float*)d_in[6];  const float* bk1 = (const float*)d_in[7];
  const float* wv1 = (const float*)d_in[8];  const float* bv1 = (const float*)d_in[9];
  const float* wo1 = (const float*)d_in[10]; const float* bo1 = (const float*)d_in[11];
  const float* pos1 = (const float*)d_in[12];
  const float* wq2 = (const float*)d_in[13]; const float* bq2 = (const float*)d_in[14];
  const float* wk2 = (const float*)d_in[15]; const float* bk2 = (const float*)d_in[16];
  const float* wv2 = (const float*)d_in[17]; const float* bv2 = (const float*)d_in[18];
  const float* wo2 = (const float*)d_in[19]; const float* bo2 = (const float*)d_in[20];
  const float* ln1g = (const float*)d_in[21]; const float* ln1b = (const float*)d_in[22];
  const float* ln2g = (const float*)d_in[23]; const float* ln2b = (const float*)d_in[24];
  const float* ln3g = (const float*)d_in[25]; const float* ln3b = (const float*)d_in[26];
  const float* wf1 = (const float*)d_in[27]; const float* bf1 = (const float*)d_in[28];
  const float* wf2 = (const float*)d_in[29]; const float* bf2 = (const float*)d_in[30];
  const float* wout = (const float*)d_in[31]; const float* bout = (const float*)d_in[32];

  char* ws = (char*)d_ws;
  u16*   WT    = (u16*)(ws + 0);             // 32MB  per-layer transposed weights
  float* maskD = (float*)(ws + 33554432);    // 8KB
  float* maskE = (float*)(ws + 33562624);    // 8KB
  u16*   WoutT = (u16*)(ws + 0);             // 65.5MB, used only at the end
  u16*   PEP   = (u16*)(ws + 67108864);      // 32MB  PE bf16 (dead after fattn_self)
  float* Part  = (float*)(ws + 67108864);    // 32MB  split-K partials (reuses PEP)
  float* X     = (float*)(ws + 100663296);   // 8MB
  float* Xa    = (float*)(ws + 109051904);   // 8MB
  float* Xb    = (float*)(ws + 117440512);   // 8MB
  u16*   Ab16  = (u16*)(ws + 134217728);     // 4MB  current GEMM-input activation
  u16*   Q     = (u16*)(ws + 138412032);     // 4MB  [g][512][64]
  u16*   Kh    = (u16*)(ws + 142606336);     // 4MB  [g][512][64]
  u16*   VT    = (u16*)(ws + 146800640);     // 8MB  [g][128][512]
  u16*   Ob16  = (u16*)(ws + 155189248);     // 4MB  merged attn out
  u16*   FFH16 = (u16*)(ws + 159383552);     // 16MB [2048][4096]
  u16*   encb  = (u16*)(ws + 176160768);     // 4MB  encoder_outputs bf16
  u16*   posb  = (u16*)(ws + 180355072);     // 384KB [6][512][64]
  float* out   = (float*)d_out;

  embed_kernel<<<2048, 256, 0, stream>>>(dec_in, emb, X, Ab16);
  conv_bf16<<<2048, 256, 0, stream>>>(enc_out, encb);
  conv_pos<<<192, 256, 0, stream>>>(pos1, posb);
  mask_kernel<<<8, 256, 0, stream>>>(dec_in, enc_in, maskD, maskE);

  for (int i = 0; i < 6; ++i) {
    const size_t oHH = (size_t)i * 1048576u, oH = (size_t)i * 1024u;
    const float* bq1i = bq1 + oH; const float* bk1i = bk1 + oH;
    const float* bv1i = bv1 + oH; const float* bo1i = bo1 + oH;
    const float* bq2i = bq2 + oH; const float* bk2i = bk2 + oH;
    const float* bv2i = bv2 + oH; const float* bo2i = bo2 + oH;
    const float* bf1i = bf1 + (size_t)i * 4096u; const float* bf2i = bf2 + oH;
    const u16* posL = posb + (size_t)i * 32768u;

    conv_layer<<<4096, 256, 0, stream>>>(
        wq1 + oHH, wk1 + oHH, wv1 + oHH, wo1 + oHH,
        wq2 + oHH, wk2 + oHH, wv2 + oHH, wo2 + oHH,
        wf1 + (size_t)i * 4194304u, wf2 + (size_t)i * 4194304u, WT);

    // ---- self attention ----
    bgemm<4, true, 4, false, false, 0, 8, 1><<<dim3(24, 16, 1), 256, 0, stream>>>(
        Ab16, 0, WT, 0, bq1i, bk1i, bv1i, nullptr, Q, Kh, VT, 0, 0, 1024, 0.125f);
    bgemm<0, true, 4, false, false, 2, 8, 1><<<dim3(4, 256, 1), 256, 0, stream>>>(
        Q, 0, posL, 0, nullptr, nullptr, nullptr, nullptr, PEP, nullptr, nullptr,
        0, 512, 64, 1.f);
    fused_attn<true><<<dim3(8, 64), 256, 0, stream>>>(Q, Kh, VT, PEP, maskD, Ob16);
    // out-proj 1, split-K=2 -> f32 partials, then fused reduce+LN1
    bgemm<0, false, 2, false, false, 0, 8, 2><<<dim3(8, 32, 2), 256, 0, stream>>>(
        Ob16, 0, WT + 3145728u, 0, nullptr, nullptr, nullptr, nullptr,
        Part, nullptr, nullptr, 2097152, 1024, 1024, 1.f);
    lnred_kernel<2><<<2048, 256, 0, stream>>>(Part, bo1i, X, ln1g + oH, ln1b + oH, Xa, Ab16);

    // ---- cross attention (round-5 separate dispatches) ----
    bgemm<1, true, 2, false, false, 0, 8, 1><<<dim3(8, 32, 1), 256, 0, stream>>>(
        Ab16, 0, WT + 4194304u, 0, bq2i, nullptr, nullptr, nullptr, Q, nullptr, nullptr,
        0, 0, 1024, 0.125f);
    bgemm<5, true, 4, false, false, 0, 8, 1><<<dim3(16, 16, 1), 256, 0, stream>>>(
        encb, 0, WT + 5242880u, 0, bk2i, bv2i, nullptr, nullptr, Kh, VT, nullptr,
        0, 0, 1024, 1.f);
    fused_attn<false><<<dim3(8, 64), 256, 0, stream>>>(Q, Kh, VT, nullptr, maskE, Ob16);
    bgemm<0, false, 2, false, false, 0, 8, 2><<<dim3(8, 32, 2), 256, 0, stream>>>(
        Ob16, 0, WT + 7340032u, 0, nullptr, nullptr, nullptr, nullptr,
        Part, nullptr, nullptr, 2097152, 1024, 1024, 1.f);
    lnred_kernel<2><<<2048, 256, 0, stream>>>(Part, bo2i, Xa, ln2g + oH, ln2b + oH, Xb, Ab16);

    // ---- FFN ----
    bgemm<0, true, 4, true, false, 0, 8, 1><<<dim3(32, 16, 1), 256, 0, stream>>>(
        Ab16, 0, WT + 8388608u, 0, bf1i, nullptr, nullptr, nullptr, FFH16, nullptr, nullptr,
        0, 4096, 1024, 1.f);
    bgemm<0, false, 4, false, false, 0, 8, 4><<<dim3(8, 16, 4), 256, 0, stream>>>(
        FFH16, 0, WT + 12582912u, 0, nullptr, nullptr, nullptr, nullptr,
        Part, nullptr, nullptr, 2097152, 1024, 4096, 1.f);
    lnred_kernel<4><<<2048, 256, 0, stream>>>(Part, bf2i, Xb, ln3g + oH, ln3b + oH, X, Ab16);
  }

  // ---- output head (f16 logits into d_out row-halves) + log_softmax ----
  conv_wout<<<8000, 256, 0, stream>>>(wout, WoutT);
  bgemm<6, false, 4, false, false, 0, 16, 1><<<dim3(250, 16, 1), 256, 0, stream>>>(
      Ab16, 0, WoutT, 0, bout, nullptr, nullptr, nullptr, out, nullptr, nullptr,
      0, 64000, 1024, 1.f);
  log_softmax_kernel<<<2048, 512, 0, stream>>>(out);
}